// Round 13
// baseline (173.381 us; speedup 1.0000x reference)
//
#include <hip/hip_runtime.h>

typedef _Float16 f16;
typedef _Float16 half8 __attribute__((ext_vector_type(8)));
typedef _Float16 half4v __attribute__((ext_vector_type(4)));
typedef __fp16 fp16x2 __attribute__((ext_vector_type(2)));
typedef float floatx4 __attribute__((ext_vector_type(4)));
typedef unsigned int uint;

constexpr int Bsz = 4, Tseq = 2048, Cdim = 1024, NH = 16, HDim = 64;
constexpr int Mtok = Bsz * Tseq;      // 8192
constexpr int NQT = Tseq / 64;        // 32 q-tiles
constexpr float QSCALE = 0.18033688f; // 0.125 * log2(e)

#define GLDS16(src, dst) __builtin_amdgcn_global_load_lds( \
    (const __attribute__((address_space(1))) void*)(src),  \
    (__attribute__((address_space(3))) void*)(dst), 16, 0, 0)

__device__ __forceinline__ float fexp2(float x) { return __builtin_amdgcn_exp2f(x); }
__device__ __forceinline__ uint pkrtz(float a, float b) {
  fp16x2 h = __builtin_amdgcn_cvt_pkrtz(a, b);
  return __builtin_bit_cast(uint, h);
}

// ---------------- fused f32 -> f16 conversion (x, W_attn, W_proj) ----------------
__global__ void cvt3_kernel(const float* __restrict__ x, const float* __restrict__ wa,
                            const float* __restrict__ wp,
                            f16* __restrict__ xh, f16* __restrict__ wah, f16* __restrict__ wph) {
  constexpr int nx = Mtok * Cdim, nwa = 3 * Cdim * Cdim, nwp = Cdim * Cdim;
  int i = (blockIdx.x * blockDim.x + threadIdx.x) * 4;
  const float* src; f16* dst; int off;
  if (i < nx)            { src = x;  dst = xh;  off = i; }
  else if (i < nx + nwa) { src = wa; dst = wah; off = i - nx; }
  else                   { src = wp; dst = wph; off = i - nx - nwa; }
  float4 v = *(const float4*)(src + off);
  half4v o;
  o[0] = (f16)v.x; o[1] = (f16)v.y; o[2] = (f16)v.z; o[3] = (f16)v.w;
  *(half4v*)(dst + off) = o;
}

// ---------------- GEMM body: C[m][n] = sum_k X[m][k] * W[n][k] ----------------
// R8 sync structure (single-buffer LDS, 2x __syncthreads per K-step) with BK=64:
// half the barrier/drain events, 32 MFMA per sync instead of 16. Staging uses the
// attn-kernel-proven map: per GLDS a wave covers 8 rows x 128B, LDS dest linear,
// XOR bank-swizzle (slot ^ row&7) pre-applied on the GLOBAL source.
// EPI 0: q/k scatter [B,H,T,HD]. EPI 1: f32 row-major. EPI 2: swapped-operand V^T.
template<int EPI>
__device__ __forceinline__ void gemm_body(char* smem,
    const f16* __restrict__ X, const f16* __restrict__ W,
    float* __restrict__ outF,
    f16* __restrict__ q_out, f16* __restrict__ k_out, f16* __restrict__ v_out,
    int N, int K, int bid)
{
  constexpr int BK = 64;   // tile rows are 128B (8 x 16B slots)
  const int tid = threadIdx.x;
  const int wave = tid >> 6;
  const int lane = tid & 63;
  const int g = lane >> 4, lm = lane & 15;
  const int nbn = N / 128;
  const int bm = bid / nbn;
  const int bn = bid % nbn;
  const int m0 = bm * 128, n0 = bn * 128;
  const int wr = wave >> 1, wc = wave & 1;

  const int srow = lane >> 3;      // 0..7 within the wave's 8-row span
  const int sslot = lane & 7;      // 16B slot within 128B row

  floatx4 acc[4][4];
#pragma unroll
  for (int i = 0; i < 4; ++i)
#pragma unroll
    for (int j = 0; j < 4; ++j) acc[i][j] = (floatx4)0.0f;

  for (int k0 = 0; k0 < K; k0 += BK) {
    __syncthreads();
#pragma unroll
    for (int t = 0; t < 4; ++t) {
      int row = wave * 8 + srow + t * 32;
      int s = sslot ^ (row & 7);   // pre-swizzled global source slot
      GLDS16(X + (size_t)(m0 + row) * K + k0 + s * 8,
             smem + (wave * 8 + t * 32) * 128);
      GLDS16(W + (size_t)(n0 + row) * K + k0 + s * 8,
             smem + 16384 + (wave * 8 + t * 32) * 128);
    }
    __syncthreads();

#pragma unroll
    for (int kk = 0; kk < 2; ++kk) {
      half8 af[4], bf[4];
#pragma unroll
      for (int i = 0; i < 4; ++i) {
        int rowa = wr * 64 + i * 16 + lm;
        af[i] = *(const half8*)(smem + rowa * 128 + 16 * ((kk * 4 + g) ^ (rowa & 7)));
        int rowb = wc * 64 + i * 16 + lm;
        bf[i] = *(const half8*)(smem + 16384 + rowb * 128 + 16 * ((kk * 4 + g) ^ (rowb & 7)));
      }
#pragma unroll
      for (int i = 0; i < 4; ++i)
#pragma unroll
        for (int j = 0; j < 4; ++j)
          acc[i][j] = __builtin_amdgcn_mfma_f32_16x16x32_f16(af[i], bf[j], acc[i][j], 0, 0, 0);
    }
  }

#pragma unroll
  for (int i = 0; i < 4; ++i) {
#pragma unroll
    for (int j = 0; j < 4; ++j) {
#pragma unroll
      for (int r = 0; r < 4; ++r) {
        int m = m0 + wr * 64 + i * 16 + 4 * g + r;
        int n = n0 + wc * 64 + j * 16 + lm;
        float v = acc[i][j][r];
        if constexpr (EPI == 1) {
          outF[(size_t)m * N + n] = v;
        } else if constexpr (EPI == 0) {
          int which = n >> 10;
          int inner = n & 1023;
          int h = inner >> 6, hd = inner & 63;
          int b = m >> 11, t = m & 2047;
          if (which == 0) {
            v *= QSCALE;  // fold softmax scale*log2e into Q
            q_out[(((size_t)(b * NH + h)) * Tseq + t) * HDim + hd] = (f16)v;
          } else {
            k_out[(((size_t)(b * NH + h)) * Tseq + t) * HDim + hd] = (f16)v;
          }
        } else {
          // swapped-operand V^T: m = W_v row (h*64+hd), n = token; lane-contiguous t
          int h = m >> 6, hd = m & 63;
          int b = n >> 11, t = n & 2047;
          v_out[(((size_t)(b * NH + h)) * HDim + hd) * Tseq + t] = (f16)v;
        }
      }
    }
  }
}

// qk projection (sbid 0..1023) + V^T projection (sbid 1024..1535), XCD-swizzled
__global__ __launch_bounds__(256)
void qkv_kernel(const f16* __restrict__ xh, const f16* __restrict__ wAh,
                f16* __restrict__ Qh, f16* __restrict__ Kh, f16* __restrict__ Vth) {
  __shared__ __align__(16) char smem[32768];
  int sbid = (blockIdx.x & 7) * 192 + (blockIdx.x >> 3);  // 1536 = 8*192, bijective
  if (sbid < 1024)
    gemm_body<0>(smem, xh, wAh, nullptr, Qh, Kh, nullptr, 2048, Cdim, sbid);
  else
    gemm_body<2>(smem, wAh + (size_t)2048 * Cdim, xh, nullptr, nullptr, nullptr, Vth,
                 Mtok, Cdim, sbid - 1024);
}

__global__ __launch_bounds__(256)
void proj_kernel(const f16* __restrict__ yh, const f16* __restrict__ wPh, float* __restrict__ out) {
  __shared__ __align__(16) char smem[32768];
  int sbid = (blockIdx.x & 7) * 64 + (blockIdx.x >> 3);   // 512 = 8*64, bijective
  gemm_body<1>(smem, yh, wPh, out, nullptr, nullptr, nullptr, Cdim, Cdim, sbid);
}

// ---------------- causal flash attention: sequential paired q-tiles ----------------
// Every block runs EXACTLY 33 uniform iterations: phase B = q-tile 31-p over kv tiles
// 0..31-p, then phase A = q-tile p over kv tiles 0..p. acc/qf registers reused across
// phases. Divide-only softmax (p = 2^s, no running max — see R7 notes).
// ONE barrier per iteration: {stage next -> compute current -> vmcnt(0) -> barrier}.
__device__ __forceinline__ void softmax_tile(floatx4* s, float& l_run,
                                             bool diag, int j0, int qg, char* pwrow, int g, int lm) {
  if (diag) {
#pragma unroll
    for (int nf = 0; nf < 4; ++nf)
#pragma unroll
      for (int r = 0; r < 4; ++r)
        if (j0 + nf * 16 + 4 * g + r > qg) s[nf][r] = -1e30f;
  }
  float rs = 0.f;
#pragma unroll
  for (int nf = 0; nf < 4; ++nf) {
    float p0 = fexp2(s[nf][0]), p1 = fexp2(s[nf][1]);
    float p2 = fexp2(s[nf][2]), p3 = fexp2(s[nf][3]);
    rs += (p0 + p1) + (p2 + p3);
    uint lo = pkrtz(p0, p1), hi = pkrtz(p2, p3);
    int slot = 2 * nf + (g >> 1);
    uint2 u; u.x = lo; u.y = hi;
    *(uint2*)(pwrow + 16 * (slot ^ (lm & 7)) + 8 * (g & 1)) = u;
  }
  l_run += rs;
}

__device__ __forceinline__ void store_o(const floatx4* acc, float l, int q0w, int g, int lm,
                                        f16* __restrict__ Y, int b, int h) {
  l += __shfl_xor(l, 16, 64);   // cross-lane l reduction, once per q-tile
  l += __shfl_xor(l, 32, 64);
#pragma unroll
  for (int r = 0; r < 4; ++r) {
    float lq = __shfl(l, 4 * g + r, 64);
    float inv = 1.0f / lq;
    int t = q0w + 4 * g + r;
    size_t base = ((size_t)(b * Tseq + t)) * Cdim + h * HDim;
#pragma unroll
    for (int ng = 0; ng < 4; ++ng)
      Y[base + ng * 16 + lm] = (f16)(acc[ng][r] * inv);
  }
}

__global__ __launch_bounds__(256)
void attn_kernel(const f16* __restrict__ Q, const f16* __restrict__ Kg,
                 const f16* __restrict__ Vt, f16* __restrict__ Y)
{
  // LDS: K dbuf 2*8192 @0 | V^T dbuf 2*8192 @16384 | P 4 waves * 2048 @32768 == 40960
  __shared__ __align__(16) char smem[40960];
  int wg = blockIdx.x;
  int lin = (wg & 7) * 128 + (wg >> 3);   // XCD-locality remap
  const int p  = lin & 15;
  const int bh = lin >> 4;
  const int itB = NQT - p;                // iterations in phase B (q-tile 31-p)
  const f16* Qb  = Q  + (size_t)bh * Tseq * HDim;
  const f16* Kb  = Kg + (size_t)bh * Tseq * HDim;
  const f16* Vtb = Vt + (size_t)bh * HDim * Tseq;   // [hd][t]

  const int tid = threadIdx.x, w = tid >> 6, lane = tid & 63;
  const int g = lane >> 4, lm = lane & 15;
  char* pwrow = smem + 32768 + w * 2048 + lm * 128;
  const int b = bh >> 4, h = bh & 15;

  // phase B state
  int q0 = (NQT - 1 - p) * 64;
  int qg = q0 + w * 16 + lm;
  half8 qf0 = *(const half8*)(Qb + (size_t)(q0 + w * 16 + lm) * HDim + g * 8);
  half8 qf1 = *(const half8*)(Qb + (size_t)(q0 + w * 16 + lm) * HDim + 32 + g * 8);

  floatx4 acc[4];
  float l = 0.f;
#pragma unroll
  for (int ng = 0; ng < 4; ++ng) acc[ng] = (floatx4)0.f;

  // staging: per GLDS instr a wave covers 8 rows (128B each); LDS dest linear,
  // bank-XOR swizzle achieved by pre-swizzling the GLOBAL source colgroup.
  const int srow = w * 8 + (lane >> 3);
  const int sslot = lane & 7;

  auto stage = [&](int j0s, int buf) {
#pragma unroll
    for (int t = 0; t < 2; ++t) {
      int row = srow + t * 32;
      int cg = sslot ^ (row & 7);
      GLDS16(Kb + (size_t)(j0s + row) * HDim + cg * 8,
             smem + buf * 8192 + (w * 8 + t * 32) * 128);
      GLDS16(Vtb + (size_t)row * Tseq + j0s + cg * 8,
             smem + 16384 + buf * 8192 + (w * 8 + t * 32) * 128);
    }
  };

  // prologue: stage tile 0, make it visible
  stage(0, 0);
  asm volatile("s_waitcnt vmcnt(0)" ::: "memory");
  __builtin_amdgcn_s_barrier();

  for (int it = 0; it < NQT + 1; ++it) {
    const bool lastB = (it == itB - 1);
    const bool last  = (it == NQT);
    const int jt = (it < itB) ? it : it - itB;
    const int j0 = jt * 64;

    if (!last) {   // issue next tile's stage; latency hides under this iter's compute
      const int itn = it + 1;
      const int jtn = (itn < itB) ? itn : itn - itB;
      stage(jtn * 64, itn & 1);
    }

    char* kb   = smem + (it & 1) * 8192;
    char* vbuf = smem + 16384 + (it & 1) * 8192;

    floatx4 s[4];
    __builtin_amdgcn_s_setprio(1);
#pragma unroll
    for (int nf = 0; nf < 4; ++nf) {
      half8 kf0 = *(const half8*)(kb + (nf * 16 + lm) * 128 + 16 * ((g)     ^ (lm & 7)));
      half8 kf1 = *(const half8*)(kb + (nf * 16 + lm) * 128 + 16 * ((4 + g) ^ (lm & 7)));
      s[nf] = __builtin_amdgcn_mfma_f32_16x16x32_f16(kf0, qf0, (floatx4)0.f, 0, 0, 0);
      s[nf] = __builtin_amdgcn_mfma_f32_16x16x32_f16(kf1, qf1, s[nf], 0, 0, 0);
    }
    __builtin_amdgcn_s_setprio(0);

    softmax_tile(s, l, lastB || last, j0, qg, pwrow, g, lm);
    half8 pa0 = *(const half8*)(pwrow + 16 * ((g)     ^ (lm & 7)));
    half8 pa1 = *(const half8*)(pwrow + 16 * ((4 + g) ^ (lm & 7)));

    __builtin_amdgcn_s_setprio(1);
#pragma unroll
    for (int c = 0; c < 2; ++c)
#pragma unroll
      for (int ng = 0; ng < 4; ++ng) {
        half8 vbf = *(const half8*)(vbuf + (ng * 16 + lm) * 128 + 16 * ((4 * c + g) ^ (lm & 7)));
        acc[ng] = __builtin_amdgcn_mfma_f32_16x16x32_f16(c ? pa1 : pa0, vbf, acc[ng], 0, 0, 0);
      }
    __builtin_amdgcn_s_setprio(0);

    // single sync point: my stage loads drained, everyone's reads of buf[it&1] done
    asm volatile("s_waitcnt vmcnt(0)" ::: "memory");
    __builtin_amdgcn_s_barrier();

    if (lastB) {
      // phase B complete: store O_B, switch registers to phase A (q-tile p)
      store_o(acc, l, q0 + 16 * w, g, lm, Y, b, h);
      q0 = p * 64;
      qg = q0 + w * 16 + lm;
      qf0 = *(const half8*)(Qb + (size_t)(q0 + w * 16 + lm) * HDim + g * 8);
      qf1 = *(const half8*)(Qb + (size_t)(q0 + w * 16 + lm) * HDim + 32 + g * 8);
      l = 0.f;
#pragma unroll
      for (int ng = 0; ng < 4; ++ng) acc[ng] = (floatx4)0.f;
    }
  }

  store_o(acc, l, q0 + 16 * w, g, lm, Y, b, h);
}

// ---------------- launcher ----------------
extern "C" void kernel_launch(void* const* d_in, const int* in_sizes, int n_in,
                              void* d_out, int out_size, void* d_ws, size_t ws_size,
                              hipStream_t stream)
{
  const float* x      = (const float*)d_in[0];
  const float* W_attn = (const float*)d_in[1];
  const float* W_proj = (const float*)d_in[2];
  float* out = (float*)d_out;

  char* ws = (char*)d_ws;
  f16* xh  = (f16*)(ws);
  f16* wAh = (f16*)(ws + (size_t)(16u << 20));
  f16* wPh = (f16*)(ws + (size_t)(22u << 20));
  f16* Qh  = (f16*)(ws + (size_t)(24u << 20));
  f16* Kh  = (f16*)(ws + (size_t)(40u << 20));
  f16* Vth = (f16*)(ws + (size_t)(56u << 20));  // V^T [B,H,HD,T]
  f16* yh  = xh;

  constexpr int ntot = (Mtok * Cdim + 3 * Cdim * Cdim + Cdim * Cdim) / 4;
  cvt3_kernel<<<(ntot + 255) / 256, 256, 0, stream>>>(x, W_attn, W_proj, xh, wAh, wPh);

  qkv_kernel<<<dim3(1536), 256, 0, stream>>>(xh, wAh, Qh, Kh, Vth);

  attn_kernel<<<dim3(1024), 256, 0, stream>>>(Qh, Kh, Vth, yh);

  proj_kernel<<<dim3(512), 256, 0, stream>>>(yh, wPh, out);
}

// Round 14
// 172.311 us; speedup vs baseline: 1.0062x; 1.0062x over previous
//
#include <hip/hip_runtime.h>

typedef _Float16 f16;
typedef _Float16 half8 __attribute__((ext_vector_type(8)));
typedef _Float16 half4v __attribute__((ext_vector_type(4)));
typedef __fp16 fp16x2 __attribute__((ext_vector_type(2)));
typedef float floatx4 __attribute__((ext_vector_type(4)));
typedef unsigned int uint;

constexpr int Bsz = 4, Tseq = 2048, Cdim = 1024, NH = 16, HDim = 64;
constexpr int Mtok = Bsz * Tseq;      // 8192
constexpr int NQT = Tseq / 64;        // 32 q-tiles
constexpr float QSCALE = 0.18033688f; // 0.125 * log2(e)

#define GLDS16(src, dst) __builtin_amdgcn_global_load_lds( \
    (const __attribute__((address_space(1))) void*)(src),  \
    (__attribute__((address_space(3))) void*)(dst), 16, 0, 0)

__device__ __forceinline__ float fexp2(float x) { return __builtin_amdgcn_exp2f(x); }
__device__ __forceinline__ uint pkrtz(float a, float b) {
  fp16x2 h = __builtin_amdgcn_cvt_pkrtz(a, b);
  return __builtin_bit_cast(uint, h);
}

// ---------------- fused f32 -> f16 conversion (x, W_attn, W_proj) ----------------
__global__ void cvt3_kernel(const float* __restrict__ x, const float* __restrict__ wa,
                            const float* __restrict__ wp,
                            f16* __restrict__ xh, f16* __restrict__ wah, f16* __restrict__ wph) {
  constexpr int nx = Mtok * Cdim, nwa = 3 * Cdim * Cdim, nwp = Cdim * Cdim;
  int i = (blockIdx.x * blockDim.x + threadIdx.x) * 4;
  const float* src; f16* dst; int off;
  if (i < nx)            { src = x;  dst = xh;  off = i; }
  else if (i < nx + nwa) { src = wa; dst = wah; off = i - nx; }
  else                   { src = wp; dst = wph; off = i - nx - nwa; }
  float4 v = *(const float4*)(src + off);
  half4v o;
  o[0] = (f16)v.x; o[1] = (f16)v.y; o[2] = (f16)v.z; o[3] = (f16)v.w;
  *(half4v*)(dst + off) = o;
}

// ---------------- GEMM body: C[m][n] = sum_k X[m][k] * W[n][k] ----------------
// R8/R12 structure verbatim (best measured): single-buffer 16KB LDS, BK=32,
// 2x __syncthreads per K-step. dbuf (R9), f32-staging (R11), BK=64 (R13) all
// regressed — occupancy & L2 locality dominate at this geometry.
// EPI 0: q/k scatter [B,H,T,HD]. EPI 1: f32 row-major. EPI 2: swapped-operand V^T.
template<int EPI>
__device__ __forceinline__ void gemm_body(f16* As, f16* Bs,
    const f16* __restrict__ X, const f16* __restrict__ W,
    float* __restrict__ outF,
    f16* __restrict__ q_out, f16* __restrict__ k_out, f16* __restrict__ v_out,
    int N, int K, int bm, int bn)
{
  constexpr int BK = 32;
  const int tid = threadIdx.x;
  const int wave = tid >> 6;
  const int lane = tid & 63;
  const int g = lane >> 4, lm = lane & 15;
  const int m0 = bm * 128, n0 = bn * 128;
  const int wr = wave >> 1, wc = wave & 1;

  floatx4 acc[4][4];
#pragma unroll
  for (int i = 0; i < 4; ++i)
#pragma unroll
    for (int j = 0; j < 4; ++j) acc[i][j] = (floatx4)0.0f;

  for (int k0 = 0; k0 < K; k0 += BK) {
    __syncthreads();
#pragma unroll
    for (int t = 0; t < 2; ++t) {
      int row = (wave * 2 + t) * 16 + (lane >> 2);
      int cg = (lane & 3) ^ ((row >> 1) & 3);   // pre-swizzled global source
      GLDS16(X + (size_t)(m0 + row) * K + k0 + cg * 8,
             (char*)As + (wave * 2 + t) * 1024);
      GLDS16(W + (size_t)(n0 + row) * K + k0 + cg * 8,
             (char*)Bs + (wave * 2 + t) * 1024);
    }
    __syncthreads();

    half8 af[4], bf[4];
#pragma unroll
    for (int i = 0; i < 4; ++i) {
      int rowa = wr * 64 + i * 16 + lm;
      int cga = g ^ ((rowa >> 1) & 3);
      af[i] = *(const half8*)((const char*)As + rowa * 64 + cga * 16);
      int rowb = wc * 64 + i * 16 + lm;
      int cgb = g ^ ((rowb >> 1) & 3);
      bf[i] = *(const half8*)((const char*)Bs + rowb * 64 + cgb * 16);
    }
#pragma unroll
    for (int i = 0; i < 4; ++i)
#pragma unroll
      for (int j = 0; j < 4; ++j)
        acc[i][j] = __builtin_amdgcn_mfma_f32_16x16x32_f16(af[i], bf[j], acc[i][j], 0, 0, 0);
  }

#pragma unroll
  for (int i = 0; i < 4; ++i) {
#pragma unroll
    for (int j = 0; j < 4; ++j) {
#pragma unroll
      for (int r = 0; r < 4; ++r) {
        int m = m0 + wr * 64 + i * 16 + 4 * g + r;
        int n = n0 + wc * 64 + j * 16 + lm;
        float v = acc[i][j][r];
        if constexpr (EPI == 1) {
          outF[(size_t)m * N + n] = v;
        } else if constexpr (EPI == 0) {
          int which = n >> 10;
          int inner = n & 1023;
          int h = inner >> 6, hd = inner & 63;
          int b = m >> 11, t = m & 2047;
          if (which == 0) {
            v *= QSCALE;  // fold softmax scale*log2e into Q
            q_out[(((size_t)(b * NH + h)) * Tseq + t) * HDim + hd] = (f16)v;
          } else {
            k_out[(((size_t)(b * NH + h)) * Tseq + t) * HDim + hd] = (f16)v;
          }
        } else {
          // swapped-operand V^T: m = W_v row (h*64+hd), n = token; lane-contiguous t
          int h = m >> 6, hd = m & 63;
          int b = n >> 11, t = n & 2047;
          v_out[(((size_t)(b * NH + h)) * HDim + hd) * Tseq + t] = (f16)v;
        }
      }
    }
  }
}

// qk projection (per-XCD 128 blocks as 4x4 super-tiles: L2 working set = 4 x-panels
// + 4 W-panels = 2MB < 4MB per-XCD L2) + V^T projection (per-XCD one W_v panel,
// streaming tokens). All remaps bijective.
__global__ __launch_bounds__(256)
void qkv_kernel(const f16* __restrict__ xh, const f16* __restrict__ wAh,
                f16* __restrict__ Qh, f16* __restrict__ Kh, f16* __restrict__ Vth) {
  __shared__ __align__(16) f16 As[128 * 32];
  __shared__ __align__(16) f16 Bs[128 * 32];
  const int x = blockIdx.x & 7;        // XCD
  const int q = blockIdx.x >> 3;       // [0,192) local id
  if (q < 128) {
    // qk region: XCD x owns bm in [8x, 8x+8), all 16 bn; walk in 4x4 chunks
    int c = q >> 4, u = q & 15;        // chunk 0..7, pos 0..15
    int bm = x * 8 + (c >> 2) * 4 + (u >> 2);
    int bn = (c & 3) * 4 + (u & 3);
    gemm_body<0>(As, Bs, xh, wAh, nullptr, Qh, Kh, nullptr, 2048, Cdim, bm, bn);
  } else {
    // V^T region: XCD x owns W_v panel x (bm = x), bn streams over tokens
    int v = q - 128;                   // [0,64)
    gemm_body<2>(As, Bs, wAh + (size_t)2048 * Cdim, xh, nullptr, nullptr, nullptr, Vth,
                 Mtok, Cdim, x, v);
  }
}

__global__ __launch_bounds__(256)
void proj_kernel(const f16* __restrict__ yh, const f16* __restrict__ wPh, float* __restrict__ out) {
  __shared__ __align__(16) f16 As[128 * 32];
  __shared__ __align__(16) f16 Bs[128 * 32];
  const int x = blockIdx.x & 7;        // XCD
  const int u = blockIdx.x >> 3;       // [0,64): XCD x owns bm in [8x,8x+8), 8 bn
  int c = u >> 4, w = u & 15;          // 4 chunks of 4x4
  int bm = x * 8 + (c >> 1) * 4 + (w >> 2);
  int bn = (c & 1) * 4 + (w & 3);
  gemm_body<1>(As, Bs, yh, wPh, out, nullptr, nullptr, nullptr, Cdim, Cdim, bm, bn);
}

// ---------------- causal flash attention: sequential paired q-tiles ----------------
// Every block runs EXACTLY 33 uniform iterations: phase B = q-tile 31-p over kv tiles
// 0..31-p, then phase A = q-tile p over kv tiles 0..p. Divide-only softmax (p = 2^s).
// ONE barrier per iteration: {stage next -> compute current -> vmcnt(0) -> barrier}.
__device__ __forceinline__ void softmax_tile(floatx4* s, float& l_run,
                                             bool diag, int j0, int qg, char* pwrow, int g, int lm) {
  if (diag) {
#pragma unroll
    for (int nf = 0; nf < 4; ++nf)
#pragma unroll
      for (int r = 0; r < 4; ++r)
        if (j0 + nf * 16 + 4 * g + r > qg) s[nf][r] = -1e30f;
  }
  float rs = 0.f;
#pragma unroll
  for (int nf = 0; nf < 4; ++nf) {
    float p0 = fexp2(s[nf][0]), p1 = fexp2(s[nf][1]);
    float p2 = fexp2(s[nf][2]), p3 = fexp2(s[nf][3]);
    rs += (p0 + p1) + (p2 + p3);
    uint lo = pkrtz(p0, p1), hi = pkrtz(p2, p3);
    int slot = 2 * nf + (g >> 1);
    uint2 u; u.x = lo; u.y = hi;
    *(uint2*)(pwrow + 16 * (slot ^ (lm & 7)) + 8 * (g & 1)) = u;
  }
  l_run += rs;
}

__device__ __forceinline__ void store_o(const floatx4* acc, float l, int q0w, int g, int lm,
                                        f16* __restrict__ Y, int b, int h) {
  l += __shfl_xor(l, 16, 64);   // cross-lane l reduction, once per q-tile
  l += __shfl_xor(l, 32, 64);
#pragma unroll
  for (int r = 0; r < 4; ++r) {
    float lq = __shfl(l, 4 * g + r, 64);
    float inv = 1.0f / lq;
    int t = q0w + 4 * g + r;
    size_t base = ((size_t)(b * Tseq + t)) * Cdim + h * HDim;
#pragma unroll
    for (int ng = 0; ng < 4; ++ng)
      Y[base + ng * 16 + lm] = (f16)(acc[ng][r] * inv);
  }
}

__global__ __launch_bounds__(256)
void attn_kernel(const f16* __restrict__ Q, const f16* __restrict__ Kg,
                 const f16* __restrict__ Vt, f16* __restrict__ Y)
{
  // LDS: K dbuf 2*8192 @0 | V^T dbuf 2*8192 @16384 | P 4 waves * 2048 @32768 == 40960
  __shared__ __align__(16) char smem[40960];
  int wg = blockIdx.x;
  int lin = (wg & 7) * 128 + (wg >> 3);   // XCD-locality remap
  const int p  = lin & 15;
  const int bh = lin >> 4;
  const int itB = NQT - p;                // iterations in phase B (q-tile 31-p)
  const f16* Qb  = Q  + (size_t)bh * Tseq * HDim;
  const f16* Kb  = Kg + (size_t)bh * Tseq * HDim;
  const f16* Vtb = Vt + (size_t)bh * HDim * Tseq;   // [hd][t]

  const int tid = threadIdx.x, w = tid >> 6, lane = tid & 63;
  const int g = lane >> 4, lm = lane & 15;
  char* pwrow = smem + 32768 + w * 2048 + lm * 128;
  const int b = bh >> 4, h = bh & 15;

  // phase B state
  int q0 = (NQT - 1 - p) * 64;
  int qg = q0 + w * 16 + lm;
  half8 qf0 = *(const half8*)(Qb + (size_t)(q0 + w * 16 + lm) * HDim + g * 8);
  half8 qf1 = *(const half8*)(Qb + (size_t)(q0 + w * 16 + lm) * HDim + 32 + g * 8);

  floatx4 acc[4];
  float l = 0.f;
#pragma unroll
  for (int ng = 0; ng < 4; ++ng) acc[ng] = (floatx4)0.f;

  // staging: per GLDS instr a wave covers 8 rows (128B each); LDS dest linear,
  // bank-XOR swizzle achieved by pre-swizzling the GLOBAL source colgroup.
  const int srow = w * 8 + (lane >> 3);
  const int sslot = lane & 7;

  auto stage = [&](int j0s, int buf) {
#pragma unroll
    for (int t = 0; t < 2; ++t) {
      int row = srow + t * 32;
      int cg = sslot ^ (row & 7);
      GLDS16(Kb + (size_t)(j0s + row) * HDim + cg * 8,
             smem + buf * 8192 + (w * 8 + t * 32) * 128);
      GLDS16(Vtb + (size_t)row * Tseq + j0s + cg * 8,
             smem + 16384 + buf * 8192 + (w * 8 + t * 32) * 128);
    }
  };

  // prologue: stage tile 0, make it visible
  stage(0, 0);
  asm volatile("s_waitcnt vmcnt(0)" ::: "memory");
  __builtin_amdgcn_s_barrier();

  for (int it = 0; it < NQT + 1; ++it) {
    const bool lastB = (it == itB - 1);
    const bool last  = (it == NQT);
    const int jt = (it < itB) ? it : it - itB;
    const int j0 = jt * 64;

    if (!last) {   // issue next tile's stage; latency hides under this iter's compute
      const int itn = it + 1;
      const int jtn = (itn < itB) ? itn : itn - itB;
      stage(jtn * 64, itn & 1);
    }

    char* kb   = smem + (it & 1) * 8192;
    char* vbuf = smem + 16384 + (it & 1) * 8192;

    floatx4 s[4];
    __builtin_amdgcn_s_setprio(1);
#pragma unroll
    for (int nf = 0; nf < 4; ++nf) {
      half8 kf0 = *(const half8*)(kb + (nf * 16 + lm) * 128 + 16 * ((g)     ^ (lm & 7)));
      half8 kf1 = *(const half8*)(kb + (nf * 16 + lm) * 128 + 16 * ((4 + g) ^ (lm & 7)));
      s[nf] = __builtin_amdgcn_mfma_f32_16x16x32_f16(kf0, qf0, (floatx4)0.f, 0, 0, 0);
      s[nf] = __builtin_amdgcn_mfma_f32_16x16x32_f16(kf1, qf1, s[nf], 0, 0, 0);
    }
    __builtin_amdgcn_s_setprio(0);

    softmax_tile(s, l, lastB || last, j0, qg, pwrow, g, lm);
    half8 pa0 = *(const half8*)(pwrow + 16 * ((g)     ^ (lm & 7)));
    half8 pa1 = *(const half8*)(pwrow + 16 * ((4 + g) ^ (lm & 7)));

    __builtin_amdgcn_s_setprio(1);
#pragma unroll
    for (int c = 0; c < 2; ++c)
#pragma unroll
      for (int ng = 0; ng < 4; ++ng) {
        half8 vbf = *(const half8*)(vbuf + (ng * 16 + lm) * 128 + 16 * ((4 * c + g) ^ (lm & 7)));
        acc[ng] = __builtin_amdgcn_mfma_f32_16x16x32_f16(c ? pa1 : pa0, vbf, acc[ng], 0, 0, 0);
      }
    __builtin_amdgcn_s_setprio(0);

    // single sync point: my stage loads drained, everyone's reads of buf[it&1] done
    asm volatile("s_waitcnt vmcnt(0)" ::: "memory");
    __builtin_amdgcn_s_barrier();

    if (lastB) {
      // phase B complete: store O_B, switch registers to phase A (q-tile p)
      store_o(acc, l, q0 + 16 * w, g, lm, Y, b, h);
      q0 = p * 64;
      qg = q0 + w * 16 + lm;
      qf0 = *(const half8*)(Qb + (size_t)(q0 + w * 16 + lm) * HDim + g * 8);
      qf1 = *(const half8*)(Qb + (size_t)(q0 + w * 16 + lm) * HDim + 32 + g * 8);
      l = 0.f;
#pragma unroll
      for (int ng = 0; ng < 4; ++ng) acc[ng] = (floatx4)0.f;
    }
  }

  store_o(acc, l, q0 + 16 * w, g, lm, Y, b, h);
}

// ---------------- launcher ----------------
extern "C" void kernel_launch(void* const* d_in, const int* in_sizes, int n_in,
                              void* d_out, int out_size, void* d_ws, size_t ws_size,
                              hipStream_t stream)
{
  const float* x      = (const float*)d_in[0];
  const float* W_attn = (const float*)d_in[1];
  const float* W_proj = (const float*)d_in[2];
  float* out = (float*)d_out;

  char* ws = (char*)d_ws;
  f16* xh  = (f16*)(ws);
  f16* wAh = (f16*)(ws + (size_t)(16u << 20));
  f16* wPh = (f16*)(ws + (size_t)(22u << 20));
  f16* Qh  = (f16*)(ws + (size_t)(24u << 20));
  f16* Kh  = (f16*)(ws + (size_t)(40u << 20));
  f16* Vth = (f16*)(ws + (size_t)(56u << 20));  // V^T [B,H,HD,T]
  f16* yh  = xh;

  constexpr int ntot = (Mtok * Cdim + 3 * Cdim * Cdim + Cdim * Cdim) / 4;
  cvt3_kernel<<<(ntot + 255) / 256, 256, 0, stream>>>(x, W_attn, W_proj, xh, wAh, wPh);

  qkv_kernel<<<dim3(1536), 256, 0, stream>>>(xh, wAh, Qh, Kh, Vth);

  attn_kernel<<<dim3(1024), 256, 0, stream>>>(Qh, Kh, Vth, yh);

  proj_kernel<<<dim3(512), 256, 0, stream>>>(yh, wPh, out);
}

// Round 15
// 168.611 us; speedup vs baseline: 1.0283x; 1.0219x over previous
//
#include <hip/hip_runtime.h>

typedef _Float16 f16;
typedef _Float16 half8 __attribute__((ext_vector_type(8)));
typedef _Float16 half4v __attribute__((ext_vector_type(4)));
typedef __fp16 fp16x2 __attribute__((ext_vector_type(2)));
typedef float floatx4 __attribute__((ext_vector_type(4)));
typedef unsigned int uint;

constexpr int Bsz = 4, Tseq = 2048, Cdim = 1024, NH = 16, HDim = 64;
constexpr int Mtok = Bsz * Tseq;      // 8192
constexpr int NQT = Tseq / 64;        // 32 q-tiles
constexpr float QSCALE = 0.18033688f; // 0.125 * log2(e)

#define GLDS16(src, dst) __builtin_amdgcn_global_load_lds( \
    (const __attribute__((address_space(1))) void*)(src),  \
    (__attribute__((address_space(3))) void*)(dst), 16, 0, 0)

__device__ __forceinline__ float fexp2(float x) { return __builtin_amdgcn_exp2f(x); }
__device__ __forceinline__ uint pkrtz(float a, float b) {
  fp16x2 h = __builtin_amdgcn_cvt_pkrtz(a, b);
  return __builtin_bit_cast(uint, h);
}
#define MFMA16(a, b, c) __builtin_amdgcn_mfma_f32_16x16x32_f16((a), (b), (c), 0, 0, 0)

// ---------------- fused f32 -> f16 conversion (x, W_attn, W_proj) ----------------
__global__ void cvt3_kernel(const float* __restrict__ x, const float* __restrict__ wa,
                            const float* __restrict__ wp,
                            f16* __restrict__ xh, f16* __restrict__ wah, f16* __restrict__ wph) {
  constexpr int nx = Mtok * Cdim, nwa = 3 * Cdim * Cdim, nwp = Cdim * Cdim;
  int i = (blockIdx.x * blockDim.x + threadIdx.x) * 4;
  const float* src; f16* dst; int off;
  if (i < nx)            { src = x;  dst = xh;  off = i; }
  else if (i < nx + nwa) { src = wa; dst = wah; off = i - nx; }
  else                   { src = wp; dst = wph; off = i - nx - nwa; }
  float4 v = *(const float4*)(src + off);
  half4v o;
  o[0] = (f16)v.x; o[1] = (f16)v.y; o[2] = (f16)v.z; o[3] = (f16)v.w;
  *(half4v*)(dst + off) = o;
}

// ============ qk projection: 256x256 tile, 8-wave, 8-phase schedule ============
// Grid 256 blocks (1/CU). K=1024, BK=64 -> 16 K-tiles, 4 phases each.
// LDS 128KB: A[2 slots][2 halves][128x64] @0, B same @64KB. Half-tile = 16KB = 2 GLDS.
// Phase p: {vmcnt; barrier; ds_read quadrant frags; 2 GLDS; lgkm0; 16 MFMA}.
// Quadrants: P0 A0xB0 (reads A0,B0), P1 A0xB1 (reads B1), P2 A1xB1 (reads A1),
// P3 A1xB0 (no reads). GLDS: Ah0(t+1)@P0, Ah1(t+1)@P1, Bh0(t+2)@P2, Bh1(t+2)@P3.
// vmcnt(4) once per K-tile at P0 (tail: vmcnt(0) at t=15). Derivation in journal.
__global__ __launch_bounds__(512, 2)
void qk8p_kernel(const f16* __restrict__ X, const f16* __restrict__ W,
                 f16* __restrict__ q_out, f16* __restrict__ k_out)
{
  __shared__ __align__(16) char smem[131072];
  constexpr int K = 1024, NT = 16;
  const int sbid = (blockIdx.x & 7) * 32 + (blockIdx.x >> 3);  // 256 = 8*32 bijective
  const int bm = sbid >> 3, bn = sbid & 7;                     // 32 x 8
  const int m0 = bm * 256, n0 = bn * 256;
  const int tid = threadIdx.x, w = tid >> 6, lane = tid & 63;
  const int wr = w >> 2, wc = w & 3;           // 2 x 4 waves, 128x64 out each
  const int g = lane >> 4, lm = lane & 15;

  // GLDS lane map: wave covers 8 rows x 128B per instr; linear dest, source
  // col-group pre-swizzled so LDS[row][slot] holds colgroup slot^(row&7).
  const int grow = lane >> 3;
  const int cg = (lane & 7) ^ grow;

  auto stage_half = [&](int op, int t, int h) {
    const f16* src = op ? W : X;
    char* base = smem + op * 65536 + (t & 1) * 32768 + h * 16384;
    const int rbase = (op ? n0 : m0) + h * 128;
#pragma unroll
    for (int r2 = 0; r2 < 2; ++r2) {
      int row = rbase + r2 * 64 + w * 8 + grow;
      GLDS16(src + (size_t)row * K + t * 64 + cg * 8,
             base + (r2 * 64 + w * 8) * 128);
    }
  };

  floatx4 acc[8][4];
#pragma unroll
  for (int i = 0; i < 8; ++i)
#pragma unroll
    for (int j = 0; j < 4; ++j) acc[i][j] = (floatx4)0.0f;

  // per-thread LDS read bases (byte offsets)
  const int sw = lm & 7;
  const char* S = smem;
  const int Abase = wr * 16384 + lm * 128;                       // + par + i*2048 + slot*16
  const int Bbase = 65536 + (wc >> 1) * 16384 + ((wc & 1) * 64 + lm) * 128;

  half8 a0[4][2], a1[4][2], b0[2][2], b1[2][2];

  // prologue: tile0 {Ah0,Ah1,Bh0,Bh1}, tile1 {Bh0,Bh1}  (12 GLDS in flight)
  stage_half(0, 0, 0); stage_half(0, 0, 1);
  stage_half(1, 0, 0); stage_half(1, 0, 1);
  stage_half(1, 1, 0); stage_half(1, 1, 1);

#pragma unroll 2
  for (int t = 0; t < NT; ++t) {
    const int par = (t & 1) * 32768;

    // ---------------- P0: quadrant A0 x B0 ----------------
    if (t == NT - 1) { asm volatile("s_waitcnt vmcnt(0)" ::: "memory"); }
    else             { asm volatile("s_waitcnt vmcnt(4)" ::: "memory"); }
    __builtin_amdgcn_s_barrier();
#pragma unroll
    for (int i = 0; i < 4; ++i)
#pragma unroll
      for (int kk = 0; kk < 2; ++kk)
        a0[i][kk] = *(const half8*)(S + par + Abase + i * 2048 + 16 * ((kk * 4 + g) ^ sw));
#pragma unroll
    for (int j = 0; j < 2; ++j)
#pragma unroll
      for (int kk = 0; kk < 2; ++kk)
        b0[j][kk] = *(const half8*)(S + par + Bbase + j * 2048 + 16 * ((kk * 4 + g) ^ sw));
    if (t + 1 < NT) stage_half(0, t + 1, 0);
    asm volatile("s_waitcnt lgkmcnt(0)" ::: "memory");
    __builtin_amdgcn_sched_barrier(0);
    __builtin_amdgcn_s_setprio(1);
#pragma unroll
    for (int i = 0; i < 4; ++i)
#pragma unroll
      for (int j = 0; j < 2; ++j)
#pragma unroll
        for (int kk = 0; kk < 2; ++kk)
          acc[i][j] = MFMA16(a0[i][kk], b0[j][kk], acc[i][j]);
    __builtin_amdgcn_s_setprio(0);

    // ---------------- P1: quadrant A0 x B1 ----------------
    __builtin_amdgcn_s_barrier();
#pragma unroll
    for (int j = 0; j < 2; ++j)
#pragma unroll
      for (int kk = 0; kk < 2; ++kk)
        b1[j][kk] = *(const half8*)(S + par + Bbase + (j + 2) * 2048 + 16 * ((kk * 4 + g) ^ sw));
    if (t + 1 < NT) stage_half(0, t + 1, 1);
    asm volatile("s_waitcnt lgkmcnt(0)" ::: "memory");
    __builtin_amdgcn_sched_barrier(0);
    __builtin_amdgcn_s_setprio(1);
#pragma unroll
    for (int i = 0; i < 4; ++i)
#pragma unroll
      for (int j = 0; j < 2; ++j)
#pragma unroll
        for (int kk = 0; kk < 2; ++kk)
          acc[i][j + 2] = MFMA16(a0[i][kk], b1[j][kk], acc[i][j + 2]);
    __builtin_amdgcn_s_setprio(0);

    // ---------------- P2: quadrant A1 x B1 ----------------
    __builtin_amdgcn_s_barrier();
#pragma unroll
    for (int i = 0; i < 4; ++i)
#pragma unroll
      for (int kk = 0; kk < 2; ++kk)
        a1[i][kk] = *(const half8*)(S + par + Abase + (i + 4) * 2048 + 16 * ((kk * 4 + g) ^ sw));
    if (t + 2 < NT) stage_half(1, t + 2, 0);
    asm volatile("s_waitcnt lgkmcnt(0)" ::: "memory");
    __builtin_amdgcn_sched_barrier(0);
    __builtin_amdgcn_s_setprio(1);
#pragma unroll
    for (int i = 0; i < 4; ++i)
#pragma unroll
      for (int j = 0; j < 2; ++j)
#pragma unroll
        for (int kk = 0; kk < 2; ++kk)
          acc[i + 4][j + 2] = MFMA16(a1[i][kk], b1[j][kk], acc[i + 4][j + 2]);
    __builtin_amdgcn_s_setprio(0);

    // ---------------- P3: quadrant A1 x B0 (no new reads) ----------------
    __builtin_amdgcn_s_barrier();
    if (t + 2 < NT) stage_half(1, t + 2, 1);
    __builtin_amdgcn_s_setprio(1);
#pragma unroll
    for (int i = 0; i < 4; ++i)
#pragma unroll
      for (int j = 0; j < 2; ++j)
#pragma unroll
        for (int kk = 0; kk < 2; ++kk)
          acc[i + 4][j] = MFMA16(a1[i][kk], b0[j][kk], acc[i + 4][j]);
    __builtin_amdgcn_s_setprio(0);
  }

  // epilogue: q/k scatter [B,H,T,HD]
#pragma unroll
  for (int i = 0; i < 8; ++i) {
#pragma unroll
    for (int j = 0; j < 4; ++j) {
#pragma unroll
      for (int r = 0; r < 4; ++r) {
        int m = m0 + wr * 128 + i * 16 + 4 * g + r;
        int n = n0 + wc * 64 + j * 16 + lm;
        float v = acc[i][j][r];
        int which = n >> 10;
        int inner = n & 1023;
        int h = inner >> 6, hd = inner & 63;
        int b = m >> 11, t = m & 2047;
        if (which == 0) {
          v *= QSCALE;
          q_out[(((size_t)(b * NH + h)) * Tseq + t) * HDim + hd] = (f16)v;
        } else {
          k_out[(((size_t)(b * NH + h)) * Tseq + t) * HDim + hd] = (f16)v;
        }
      }
    }
  }
}

// ---------------- 128^2 GEMM body (R8 structure, best measured) ----------------
// EPI 1: f32 row-major. EPI 2: swapped-operand V^T.
template<int EPI>
__device__ __forceinline__ void gemm_body(f16* As, f16* Bs,
    const f16* __restrict__ X, const f16* __restrict__ W,
    float* __restrict__ outF, f16* __restrict__ v_out,
    int N, int K, int bm, int bn)
{
  constexpr int BK = 32;
  const int tid = threadIdx.x;
  const int wave = tid >> 6;
  const int lane = tid & 63;
  const int g = lane >> 4, lm = lane & 15;
  const int m0 = bm * 128, n0 = bn * 128;
  const int wr = wave >> 1, wc = wave & 1;

  floatx4 acc[4][4];
#pragma unroll
  for (int i = 0; i < 4; ++i)
#pragma unroll
    for (int j = 0; j < 4; ++j) acc[i][j] = (floatx4)0.0f;

  for (int k0 = 0; k0 < K; k0 += BK) {
    __syncthreads();
#pragma unroll
    for (int t = 0; t < 2; ++t) {
      int row = (wave * 2 + t) * 16 + (lane >> 2);
      int cg = (lane & 3) ^ ((row >> 1) & 3);
      GLDS16(X + (size_t)(m0 + row) * K + k0 + cg * 8,
             (char*)As + (wave * 2 + t) * 1024);
      GLDS16(W + (size_t)(n0 + row) * K + k0 + cg * 8,
             (char*)Bs + (wave * 2 + t) * 1024);
    }
    __syncthreads();

    half8 af[4], bf[4];
#pragma unroll
    for (int i = 0; i < 4; ++i) {
      int rowa = wr * 64 + i * 16 + lm;
      int cga = g ^ ((rowa >> 1) & 3);
      af[i] = *(const half8*)((const char*)As + rowa * 64 + cga * 16);
      int rowb = wc * 64 + i * 16 + lm;
      int cgb = g ^ ((rowb >> 1) & 3);
      bf[i] = *(const half8*)((const char*)Bs + rowb * 64 + cgb * 16);
    }
#pragma unroll
    for (int i = 0; i < 4; ++i)
#pragma unroll
      for (int j = 0; j < 4; ++j)
        acc[i][j] = MFMA16(af[i], bf[j], acc[i][j]);
  }

#pragma unroll
  for (int i = 0; i < 4; ++i) {
#pragma unroll
    for (int j = 0; j < 4; ++j) {
#pragma unroll
      for (int r = 0; r < 4; ++r) {
        int m = m0 + wr * 64 + i * 16 + 4 * g + r;
        int n = n0 + wc * 64 + j * 16 + lm;
        float v = acc[i][j][r];
        if constexpr (EPI == 1) {
          outF[(size_t)m * N + n] = v;
        } else {
          int h = m >> 6, hd = m & 63;
          int b = n >> 11, t = n & 2047;
          v_out[(((size_t)(b * NH + h)) * HDim + hd) * Tseq + t] = (f16)v;
        }
      }
    }
  }
}

// V^T projection: M=1024 (W_v rows, 8 bm), N=8192 (tokens, 64 bn); XCD x owns panel x
__global__ __launch_bounds__(256)
void vt_kernel(const f16* __restrict__ xh, const f16* __restrict__ wVh, f16* __restrict__ Vth) {
  __shared__ __align__(16) f16 As[128 * 32];
  __shared__ __align__(16) f16 Bs[128 * 32];
  int bm = blockIdx.x & 7, bn = blockIdx.x >> 3;
  gemm_body<2>(As, Bs, wVh, xh, nullptr, Vth, Mtok, Cdim, bm, bn);
}

__global__ __launch_bounds__(256)
void proj_kernel(const f16* __restrict__ yh, const f16* __restrict__ wPh, float* __restrict__ out) {
  __shared__ __align__(16) f16 As[128 * 32];
  __shared__ __align__(16) f16 Bs[128 * 32];
  const int x = blockIdx.x & 7;
  const int u = blockIdx.x >> 3;
  int c = u >> 4, ww = u & 15;
  int bm = x * 8 + (c >> 1) * 4 + (ww >> 2);
  int bn = (c & 1) * 4 + (ww & 3);
  gemm_body<1>(As, Bs, yh, wPh, out, nullptr, Cdim, Cdim, bm, bn);
}

// ---------------- causal flash attention (R12 form, unchanged) ----------------
__device__ __forceinline__ void softmax_tile(floatx4* s, float& l_run,
                                             bool diag, int j0, int qg, char* pwrow, int g, int lm) {
  if (diag) {
#pragma unroll
    for (int nf = 0; nf < 4; ++nf)
#pragma unroll
      for (int r = 0; r < 4; ++r)
        if (j0 + nf * 16 + 4 * g + r > qg) s[nf][r] = -1e30f;
  }
  float rs = 0.f;
#pragma unroll
  for (int nf = 0; nf < 4; ++nf) {
    float p0 = fexp2(s[nf][0]), p1 = fexp2(s[nf][1]);
    float p2 = fexp2(s[nf][2]), p3 = fexp2(s[nf][3]);
    rs += (p0 + p1) + (p2 + p3);
    uint lo = pkrtz(p0, p1), hi = pkrtz(p2, p3);
    int slot = 2 * nf + (g >> 1);
    uint2 u; u.x = lo; u.y = hi;
    *(uint2*)(pwrow + 16 * (slot ^ (lm & 7)) + 8 * (g & 1)) = u;
  }
  l_run += rs;
}

__device__ __forceinline__ void store_o(const floatx4* acc, float l, int q0w, int g, int lm,
                                        f16* __restrict__ Y, int b, int h) {
  l += __shfl_xor(l, 16, 64);
  l += __shfl_xor(l, 32, 64);
#pragma unroll
  for (int r = 0; r < 4; ++r) {
    float lq = __shfl(l, 4 * g + r, 64);
    float inv = 1.0f / lq;
    int t = q0w + 4 * g + r;
    size_t base = ((size_t)(b * Tseq + t)) * Cdim + h * HDim;
#pragma unroll
    for (int ng = 0; ng < 4; ++ng)
      Y[base + ng * 16 + lm] = (f16)(acc[ng][r] * inv);
  }
}

__global__ __launch_bounds__(256)
void attn_kernel(const f16* __restrict__ Q, const f16* __restrict__ Kg,
                 const f16* __restrict__ Vt, f16* __restrict__ Y)
{
  __shared__ __align__(16) char smem[40960];
  int wg = blockIdx.x;
  int lin = (wg & 7) * 128 + (wg >> 3);
  const int p  = lin & 15;
  const int bh = lin >> 4;
  const int itB = NQT - p;
  const f16* Qb  = Q  + (size_t)bh * Tseq * HDim;
  const f16* Kb  = Kg + (size_t)bh * Tseq * HDim;
  const f16* Vtb = Vt + (size_t)bh * HDim * Tseq;

  const int tid = threadIdx.x, w = tid >> 6, lane = tid & 63;
  const int g = lane >> 4, lm = lane & 15;
  char* pwrow = smem + 32768 + w * 2048 + lm * 128;
  const int b = bh >> 4, h = bh & 15;

  int q0 = (NQT - 1 - p) * 64;
  int qg = q0 + w * 16 + lm;
  half8 qf0 = *(const half8*)(Qb + (size_t)(q0 + w * 16 + lm) * HDim + g * 8);
  half8 qf1 = *(const half8*)(Qb + (size_t)(q0 + w * 16 + lm) * HDim + 32 + g * 8);

  floatx4 acc[4];
  float l = 0.f;
#pragma unroll
  for (int ng = 0; ng < 4; ++ng) acc[ng] = (floatx4)0.f;

  const int srow = w * 8 + (lane >> 3);
  const int sslot = lane & 7;

  auto stage = [&](int j0s, int buf) {
#pragma unroll
    for (int t = 0; t < 2; ++t) {
      int row = srow + t * 32;
      int cg = sslot ^ (row & 7);
      GLDS16(Kb + (size_t)(j0s + row) * HDim + cg * 8,
             smem + buf * 8192 + (w * 8 + t * 32) * 128);
      GLDS16(Vtb + (size_t)row * Tseq + j0s + cg * 8,
             smem + 16384 + buf * 8192 + (w * 8 + t * 32) * 128);
    }
  };

  stage(0, 0);
  asm volatile("s_waitcnt vmcnt(0)" ::: "memory");
  __builtin_amdgcn_s_barrier();

  for (int it = 0; it < NQT + 1; ++it) {
    const bool lastB = (it == itB - 1);
    const bool last  = (it == NQT);
    const int jt = (it < itB) ? it : it - itB;
    const int j0 = jt * 64;

    if (!last) {
      const int itn = it + 1;
      const int jtn = (itn < itB) ? itn : itn - itB;
      stage(jtn * 64, itn & 1);
    }

    char* kb   = smem + (it & 1) * 8192;
    char* vbuf = smem + 16384 + (it & 1) * 8192;

    floatx4 s[4];
    __builtin_amdgcn_s_setprio(1);
#pragma unroll
    for (int nf = 0; nf < 4; ++nf) {
      half8 kf0 = *(const half8*)(kb + (nf * 16 + lm) * 128 + 16 * ((g)     ^ (lm & 7)));
      half8 kf1 = *(const half8*)(kb + (nf * 16 + lm) * 128 + 16 * ((4 + g) ^ (lm & 7)));
      s[nf] = MFMA16(kf0, qf0, (floatx4)0.f);
      s[nf] = MFMA16(kf1, qf1, s[nf]);
    }
    __builtin_amdgcn_s_setprio(0);

    softmax_tile(s, l, lastB || last, j0, qg, pwrow, g, lm);
    half8 pa0 = *(const half8*)(pwrow + 16 * ((g)     ^ (lm & 7)));
    half8 pa1 = *(const half8*)(pwrow + 16 * ((4 + g) ^ (lm & 7)));

    __builtin_amdgcn_s_setprio(1);
#pragma unroll
    for (int c = 0; c < 2; ++c)
#pragma unroll
      for (int ng = 0; ng < 4; ++ng) {
        half8 vbf = *(const half8*)(vbuf + (ng * 16 + lm) * 128 + 16 * ((4 * c + g) ^ (lm & 7)));
        acc[ng] = MFMA16(c ? pa1 : pa0, vbf, acc[ng]);
      }
    __builtin_amdgcn_s_setprio(0);

    asm volatile("s_waitcnt vmcnt(0)" ::: "memory");
    __builtin_amdgcn_s_barrier();

    if (lastB) {
      store_o(acc, l, q0 + 16 * w, g, lm, Y, b, h);
      q0 = p * 64;
      qg = q0 + w * 16 + lm;
      qf0 = *(const half8*)(Qb + (size_t)(q0 + w * 16 + lm) * HDim + g * 8);
      qf1 = *(const half8*)(Qb + (size_t)(q0 + w * 16 + lm) * HDim + 32 + g * 8);
      l = 0.f;
#pragma unroll
      for (int ng = 0; ng < 4; ++ng) acc[ng] = (floatx4)0.f;
    }
  }

  store_o(acc, l, q0 + 16 * w, g, lm, Y, b, h);
}

// ---------------- launcher ----------------
extern "C" void kernel_launch(void* const* d_in, const int* in_sizes, int n_in,
                              void* d_out, int out_size, void* d_ws, size_t ws_size,
                              hipStream_t stream)
{
  const float* x      = (const float*)d_in[0];
  const float* W_attn = (const float*)d_in[1];
  const float* W_proj = (const float*)d_in[2];
  float* out = (float*)d_out;

  char* ws = (char*)d_ws;
  f16* xh  = (f16*)(ws);
  f16* wAh = (f16*)(ws + (size_t)(16u << 20));
  f16* wPh = (f16*)(ws + (size_t)(22u << 20));
  f16* Qh  = (f16*)(ws + (size_t)(24u << 20));
  f16* Kh  = (f16*)(ws + (size_t)(40u << 20));
  f16* Vth = (f16*)(ws + (size_t)(56u << 20));  // V^T [B,H,HD,T]
  f16* yh  = xh;

  constexpr int ntot = (Mtok * Cdim + 3 * Cdim * Cdim + Cdim * Cdim) / 4;
  cvt3_kernel<<<(ntot + 255) / 256, 256, 0, stream>>>(x, W_attn, W_proj, xh, wAh, wPh);

  qk8p_kernel<<<dim3(256), 512, 0, stream>>>(xh, wAh, Qh, Kh);

  vt_kernel<<<dim3(512), 256, 0, stream>>>(xh, wAh + (size_t)2048 * Cdim, Vth);

  attn_kernel<<<dim3(1024), 256, 0, stream>>>(Qh, Kh, Vth, yh);

  proj_kernel<<<dim3(512), 256, 0, stream>>>(yh, wPh, out);
}

// Round 16
// 168.173 us; speedup vs baseline: 1.0310x; 1.0026x over previous
//
#include <hip/hip_runtime.h>

typedef _Float16 f16;
typedef _Float16 half8 __attribute__((ext_vector_type(8)));
typedef _Float16 half4v __attribute__((ext_vector_type(4)));
typedef __fp16 fp16x2 __attribute__((ext_vector_type(2)));
typedef float floatx4 __attribute__((ext_vector_type(4)));
typedef unsigned int uint;

constexpr int Bsz = 4, Tseq = 2048, Cdim = 1024, NH = 16, HDim = 64;
constexpr int Mtok = Bsz * Tseq;      // 8192
constexpr int NQT = Tseq / 64;        // 32 q-tiles
constexpr float QSCALE = 0.18033688f; // 0.125 * log2(e)

#define GLDS16(src, dst) __builtin_amdgcn_global_load_lds( \
    (const __attribute__((address_space(1))) void*)(src),  \
    (__attribute__((address_space(3))) void*)(dst), 16, 0, 0)

__device__ __forceinline__ float fexp2(float x) { return __builtin_amdgcn_exp2f(x); }
__device__ __forceinline__ uint pkrtz(float a, float b) {
  fp16x2 h = __builtin_amdgcn_cvt_pkrtz(a, b);
  return __builtin_bit_cast(uint, h);
}
#define MFMA16(a, b, c) __builtin_amdgcn_mfma_f32_16x16x32_f16((a), (b), (c), 0, 0, 0)

// ---------------- fused f32 -> f16 conversion (x, W_attn, W_proj) ----------------
__global__ void cvt3_kernel(const float* __restrict__ x, const float* __restrict__ wa,
                            const float* __restrict__ wp,
                            f16* __restrict__ xh, f16* __restrict__ wah, f16* __restrict__ wph) {
  constexpr int nx = Mtok * Cdim, nwa = 3 * Cdim * Cdim, nwp = Cdim * Cdim;
  int i = (blockIdx.x * blockDim.x + threadIdx.x) * 4;
  const float* src; f16* dst; int off;
  if (i < nx)            { src = x;  dst = xh;  off = i; }
  else if (i < nx + nwa) { src = wa; dst = wah; off = i - nx; }
  else                   { src = wp; dst = wph; off = i - nx - nwa; }
  float4 v = *(const float4*)(src + off);
  half4v o;
  o[0] = (f16)v.x; o[1] = (f16)v.y; o[2] = (f16)v.z; o[3] = (f16)v.w;
  *(half4v*)(dst + off) = o;
}

// ============ qk projection: 256x256 tile, 8-wave, 8-phase schedule ============
// (R15, verified: MfmaUtil-class win, ~32us) Grid 256 blocks (1/CU). BK=64, 16 K-tiles.
__global__ __launch_bounds__(512, 2)
void qk8p_kernel(const f16* __restrict__ X, const f16* __restrict__ W,
                 f16* __restrict__ q_out, f16* __restrict__ k_out)
{
  __shared__ __align__(16) char smem[131072];
  constexpr int K = 1024, NT = 16;
  const int sbid = (blockIdx.x & 7) * 32 + (blockIdx.x >> 3);  // 256 = 8*32 bijective
  const int bm = sbid >> 3, bn = sbid & 7;                     // 32 x 8
  const int m0 = bm * 256, n0 = bn * 256;
  const int tid = threadIdx.x, w = tid >> 6, lane = tid & 63;
  const int wr = w >> 2, wc = w & 3;           // 2 x 4 waves, 128x64 out each
  const int g = lane >> 4, lm = lane & 15;

  const int grow = lane >> 3;
  const int cg = (lane & 7) ^ grow;

  auto stage_half = [&](int op, int t, int h) {
    const f16* src = op ? W : X;
    char* base = smem + op * 65536 + (t & 1) * 32768 + h * 16384;
    const int rbase = (op ? n0 : m0) + h * 128;
#pragma unroll
    for (int r2 = 0; r2 < 2; ++r2) {
      int row = rbase + r2 * 64 + w * 8 + grow;
      GLDS16(src + (size_t)row * K + t * 64 + cg * 8,
             base + (r2 * 64 + w * 8) * 128);
    }
  };

  floatx4 acc[8][4];
#pragma unroll
  for (int i = 0; i < 8; ++i)
#pragma unroll
    for (int j = 0; j < 4; ++j) acc[i][j] = (floatx4)0.0f;

  const int sw = lm & 7;
  const char* S = smem;
  const int Abase = wr * 16384 + lm * 128;
  const int Bbase = 65536 + (wc >> 1) * 16384 + ((wc & 1) * 64 + lm) * 128;

  half8 a0[4][2], a1[4][2], b0[2][2], b1[2][2];

  stage_half(0, 0, 0); stage_half(0, 0, 1);
  stage_half(1, 0, 0); stage_half(1, 0, 1);
  stage_half(1, 1, 0); stage_half(1, 1, 1);

#pragma unroll 2
  for (int t = 0; t < NT; ++t) {
    const int par = (t & 1) * 32768;

    // P0: A0 x B0
    if (t == NT - 1) { asm volatile("s_waitcnt vmcnt(0)" ::: "memory"); }
    else             { asm volatile("s_waitcnt vmcnt(4)" ::: "memory"); }
    __builtin_amdgcn_s_barrier();
#pragma unroll
    for (int i = 0; i < 4; ++i)
#pragma unroll
      for (int kk = 0; kk < 2; ++kk)
        a0[i][kk] = *(const half8*)(S + par + Abase + i * 2048 + 16 * ((kk * 4 + g) ^ sw));
#pragma unroll
    for (int j = 0; j < 2; ++j)
#pragma unroll
      for (int kk = 0; kk < 2; ++kk)
        b0[j][kk] = *(const half8*)(S + par + Bbase + j * 2048 + 16 * ((kk * 4 + g) ^ sw));
    if (t + 1 < NT) stage_half(0, t + 1, 0);
    asm volatile("s_waitcnt lgkmcnt(0)" ::: "memory");
    __builtin_amdgcn_sched_barrier(0);
    __builtin_amdgcn_s_setprio(1);
#pragma unroll
    for (int i = 0; i < 4; ++i)
#pragma unroll
      for (int j = 0; j < 2; ++j)
#pragma unroll
        for (int kk = 0; kk < 2; ++kk)
          acc[i][j] = MFMA16(a0[i][kk], b0[j][kk], acc[i][j]);
    __builtin_amdgcn_s_setprio(0);

    // P1: A0 x B1
    __builtin_amdgcn_s_barrier();
#pragma unroll
    for (int j = 0; j < 2; ++j)
#pragma unroll
      for (int kk = 0; kk < 2; ++kk)
        b1[j][kk] = *(const half8*)(S + par + Bbase + (j + 2) * 2048 + 16 * ((kk * 4 + g) ^ sw));
    if (t + 1 < NT) stage_half(0, t + 1, 1);
    asm volatile("s_waitcnt lgkmcnt(0)" ::: "memory");
    __builtin_amdgcn_sched_barrier(0);
    __builtin_amdgcn_s_setprio(1);
#pragma unroll
    for (int i = 0; i < 4; ++i)
#pragma unroll
      for (int j = 0; j < 2; ++j)
#pragma unroll
        for (int kk = 0; kk < 2; ++kk)
          acc[i][j + 2] = MFMA16(a0[i][kk], b1[j][kk], acc[i][j + 2]);
    __builtin_amdgcn_s_setprio(0);

    // P2: A1 x B1
    __builtin_amdgcn_s_barrier();
#pragma unroll
    for (int i = 0; i < 4; ++i)
#pragma unroll
      for (int kk = 0; kk < 2; ++kk)
        a1[i][kk] = *(const half8*)(S + par + Abase + (i + 4) * 2048 + 16 * ((kk * 4 + g) ^ sw));
    if (t + 2 < NT) stage_half(1, t + 2, 0);
    asm volatile("s_waitcnt lgkmcnt(0)" ::: "memory");
    __builtin_amdgcn_sched_barrier(0);
    __builtin_amdgcn_s_setprio(1);
#pragma unroll
    for (int i = 0; i < 4; ++i)
#pragma unroll
      for (int j = 0; j < 2; ++j)
#pragma unroll
        for (int kk = 0; kk < 2; ++kk)
          acc[i + 4][j + 2] = MFMA16(a1[i][kk], b1[j][kk], acc[i + 4][j + 2]);
    __builtin_amdgcn_s_setprio(0);

    // P3: A1 x B0
    __builtin_amdgcn_s_barrier();
    if (t + 2 < NT) stage_half(1, t + 2, 1);
    __builtin_amdgcn_s_setprio(1);
#pragma unroll
    for (int i = 0; i < 4; ++i)
#pragma unroll
      for (int j = 0; j < 2; ++j)
#pragma unroll
        for (int kk = 0; kk < 2; ++kk)
          acc[i + 4][j] = MFMA16(a1[i][kk], b0[j][kk], acc[i + 4][j]);
    __builtin_amdgcn_s_setprio(0);
  }

#pragma unroll
  for (int i = 0; i < 8; ++i) {
#pragma unroll
    for (int j = 0; j < 4; ++j) {
#pragma unroll
      for (int r = 0; r < 4; ++r) {
        int m = m0 + wr * 128 + i * 16 + 4 * g + r;
        int n = n0 + wc * 64 + j * 16 + lm;
        float v = acc[i][j][r];
        int which = n >> 10;
        int inner = n & 1023;
        int h = inner >> 6, hd = inner & 63;
        int b = m >> 11, t = m & 2047;
        if (which == 0) {
          v *= QSCALE;
          q_out[(((size_t)(b * NH + h)) * Tseq + t) * HDim + hd] = (f16)v;
        } else {
          k_out[(((size_t)(b * NH + h)) * Tseq + t) * HDim + hd] = (f16)v;
        }
      }
    }
  }
}

// ---------------- 128^2 GEMM body (R8 structure, best measured) ----------------
template<int EPI>
__device__ __forceinline__ void gemm_body(f16* As, f16* Bs,
    const f16* __restrict__ X, const f16* __restrict__ W,
    float* __restrict__ outF, f16* __restrict__ v_out,
    int N, int K, int bm, int bn)
{
  constexpr int BK = 32;
  const int tid = threadIdx.x;
  const int wave = tid >> 6;
  const int lane = tid & 63;
  const int g = lane >> 4, lm = lane & 15;
  const int m0 = bm * 128, n0 = bn * 128;
  const int wr = wave >> 1, wc = wave & 1;

  floatx4 acc[4][4];
#pragma unroll
  for (int i = 0; i < 4; ++i)
#pragma unroll
    for (int j = 0; j < 4; ++j) acc[i][j] = (floatx4)0.0f;

  for (int k0 = 0; k0 < K; k0 += BK) {
    __syncthreads();
#pragma unroll
    for (int t = 0; t < 2; ++t) {
      int row = (wave * 2 + t) * 16 + (lane >> 2);
      int cg = (lane & 3) ^ ((row >> 1) & 3);
      GLDS16(X + (size_t)(m0 + row) * K + k0 + cg * 8,
             (char*)As + (wave * 2 + t) * 1024);
      GLDS16(W + (size_t)(n0 + row) * K + k0 + cg * 8,
             (char*)Bs + (wave * 2 + t) * 1024);
    }
    __syncthreads();

    half8 af[4], bf[4];
#pragma unroll
    for (int i = 0; i < 4; ++i) {
      int rowa = wr * 64 + i * 16 + lm;
      int cga = g ^ ((rowa >> 1) & 3);
      af[i] = *(const half8*)((const char*)As + rowa * 64 + cga * 16);
      int rowb = wc * 64 + i * 16 + lm;
      int cgb = g ^ ((rowb >> 1) & 3);
      bf[i] = *(const half8*)((const char*)Bs + rowb * 64 + cgb * 16);
    }
#pragma unroll
    for (int i = 0; i < 4; ++i)
#pragma unroll
      for (int j = 0; j < 4; ++j)
        acc[i][j] = MFMA16(af[i], bf[j], acc[i][j]);
  }

#pragma unroll
  for (int i = 0; i < 4; ++i) {
#pragma unroll
    for (int j = 0; j < 4; ++j) {
#pragma unroll
      for (int r = 0; r < 4; ++r) {
        int m = m0 + wr * 64 + i * 16 + 4 * g + r;
        int n = n0 + wc * 64 + j * 16 + lm;
        float v = acc[i][j][r];
        if constexpr (EPI == 1) {
          outF[(size_t)m * N + n] = v;
        } else {
          int h = m >> 6, hd = m & 63;
          int b = n >> 11, t = n & 2047;
          v_out[(((size_t)(b * NH + h)) * HDim + hd) * Tseq + t] = (f16)v;
        }
      }
    }
  }
}

__global__ __launch_bounds__(256)
void vt_kernel(const f16* __restrict__ xh, const f16* __restrict__ wVh, f16* __restrict__ Vth) {
  __shared__ __align__(16) f16 As[128 * 32];
  __shared__ __align__(16) f16 Bs[128 * 32];
  int bm = blockIdx.x & 7, bn = blockIdx.x >> 3;
  gemm_body<2>(As, Bs, wVh, xh, nullptr, Vth, Mtok, Cdim, bm, bn);
}

__global__ __launch_bounds__(256)
void proj_kernel(const f16* __restrict__ yh, const f16* __restrict__ wPh, float* __restrict__ out) {
  __shared__ __align__(16) f16 As[128 * 32];
  __shared__ __align__(16) f16 Bs[128 * 32];
  const int x = blockIdx.x & 7;
  const int u = blockIdx.x >> 3;
  int c = u >> 4, ww = u & 15;
  int bm = x * 8 + (c >> 1) * 4 + (ww >> 2);
  int bn = (c & 1) * 4 + (ww & 3);
  gemm_body<1>(As, Bs, yh, wPh, out, nullptr, Cdim, Cdim, bm, bn);
}

// ---------------- causal flash attention: MFMA-computed softmax denominator ----
// l is computed by the matrix pipe: acc5 = MFMA(P, ones) accumulates Sum_kv P[q][kv]
// per q-row in every lane — removes the rs add-tree, l_run, both per-tile
// shfl_xor, and all epilogue shuffles (VALU was the pressure pipe at 50%).
__device__ __forceinline__ void softmax_tile(floatx4* s,
                                             bool diag, int j0, int qg, char* pwrow, int g, int lm) {
  if (diag) {
#pragma unroll
    for (int nf = 0; nf < 4; ++nf)
#pragma unroll
      for (int r = 0; r < 4; ++r)
        if (j0 + nf * 16 + 4 * g + r > qg) s[nf][r] = -1e30f;
  }
#pragma unroll
  for (int nf = 0; nf < 4; ++nf) {
    float p0 = fexp2(s[nf][0]), p1 = fexp2(s[nf][1]);
    float p2 = fexp2(s[nf][2]), p3 = fexp2(s[nf][3]);
    uint lo = pkrtz(p0, p1), hi = pkrtz(p2, p3);
    int slot = 2 * nf + (g >> 1);
    uint2 u; u.x = lo; u.y = hi;
    *(uint2*)(pwrow + 16 * (slot ^ (lm & 7)) + 8 * (g & 1)) = u;
  }
}

__device__ __forceinline__ void store_o(const floatx4* acc, const floatx4 l5, int q0w,
                                        int g, int lm, f16* __restrict__ Y, int b, int h) {
#pragma unroll
  for (int r = 0; r < 4; ++r) {
    float inv = 1.0f / l5[r];
    int t = q0w + 4 * g + r;
    size_t base = ((size_t)(b * Tseq + t)) * Cdim + h * HDim;
#pragma unroll
    for (int ng = 0; ng < 4; ++ng)
      Y[base + ng * 16 + lm] = (f16)(acc[ng][r] * inv);
  }
}

__global__ __launch_bounds__(256)
void attn_kernel(const f16* __restrict__ Q, const f16* __restrict__ Kg,
                 const f16* __restrict__ Vt, f16* __restrict__ Y)
{
  __shared__ __align__(16) char smem[40960];
  int wg = blockIdx.x;
  int lin = (wg & 7) * 128 + (wg >> 3);
  const int p  = lin & 15;
  const int bh = lin >> 4;
  const int itB = NQT - p;
  const f16* Qb  = Q  + (size_t)bh * Tseq * HDim;
  const f16* Kb  = Kg + (size_t)bh * Tseq * HDim;
  const f16* Vtb = Vt + (size_t)bh * HDim * Tseq;

  const int tid = threadIdx.x, w = tid >> 6, lane = tid & 63;
  const int g = lane >> 4, lm = lane & 15;
  char* pwrow = smem + 32768 + w * 2048 + lm * 128;
  const int b = bh >> 4, h = bh & 15;

  // constant all-ones B-fragment for the l-MFMA (registers only)
  half8 ones;
#pragma unroll
  for (int i = 0; i < 8; ++i) ones[i] = (f16)1.0f;

  int q0 = (NQT - 1 - p) * 64;
  int qg = q0 + w * 16 + lm;
  half8 qf0 = *(const half8*)(Qb + (size_t)(q0 + w * 16 + lm) * HDim + g * 8);
  half8 qf1 = *(const half8*)(Qb + (size_t)(q0 + w * 16 + lm) * HDim + 32 + g * 8);

  floatx4 acc[4], acc5;
  acc5 = (floatx4)0.f;
#pragma unroll
  for (int ng = 0; ng < 4; ++ng) acc[ng] = (floatx4)0.f;

  const int srow = w * 8 + (lane >> 3);
  const int sslot = lane & 7;

  auto stage = [&](int j0s, int buf) {
#pragma unroll
    for (int t = 0; t < 2; ++t) {
      int row = srow + t * 32;
      int cg = sslot ^ (row & 7);
      GLDS16(Kb + (size_t)(j0s + row) * HDim + cg * 8,
             smem + buf * 8192 + (w * 8 + t * 32) * 128);
      GLDS16(Vtb + (size_t)row * Tseq + j0s + cg * 8,
             smem + 16384 + buf * 8192 + (w * 8 + t * 32) * 128);
    }
  };

  stage(0, 0);
  asm volatile("s_waitcnt vmcnt(0)" ::: "memory");
  __builtin_amdgcn_s_barrier();

  for (int it = 0; it < NQT + 1; ++it) {
    const bool lastB = (it == itB - 1);
    const bool last  = (it == NQT);
    const int jt = (it < itB) ? it : it - itB;
    const int j0 = jt * 64;

    if (!last) {
      const int itn = it + 1;
      const int jtn = (itn < itB) ? itn : itn - itB;
      stage(jtn * 64, itn & 1);
    }

    char* kb   = smem + (it & 1) * 8192;
    char* vbuf = smem + 16384 + (it & 1) * 8192;

    floatx4 s[4];
    __builtin_amdgcn_s_setprio(1);
#pragma unroll
    for (int nf = 0; nf < 4; ++nf) {
      half8 kf0 = *(const half8*)(kb + (nf * 16 + lm) * 128 + 16 * ((g)     ^ (lm & 7)));
      half8 kf1 = *(const half8*)(kb + (nf * 16 + lm) * 128 + 16 * ((4 + g) ^ (lm & 7)));
      s[nf] = MFMA16(kf0, qf0, (floatx4)0.f);
      s[nf] = MFMA16(kf1, qf1, s[nf]);
    }
    __builtin_amdgcn_s_setprio(0);

    softmax_tile(s, lastB || last, j0, qg, pwrow, g, lm);
    half8 pa0 = *(const half8*)(pwrow + 16 * ((g)     ^ (lm & 7)));
    half8 pa1 = *(const half8*)(pwrow + 16 * ((4 + g) ^ (lm & 7)));

    __builtin_amdgcn_s_setprio(1);
    acc5 = MFMA16(pa0, ones, acc5);   // l-denominator via matrix pipe
    acc5 = MFMA16(pa1, ones, acc5);
#pragma unroll
    for (int c = 0; c < 2; ++c)
#pragma unroll
      for (int ng = 0; ng < 4; ++ng) {
        half8 vbf = *(const half8*)(vbuf + (ng * 16 + lm) * 128 + 16 * ((4 * c + g) ^ (lm & 7)));
        acc[ng] = MFMA16(c ? pa1 : pa0, vbf, acc[ng]);
      }
    __builtin_amdgcn_s_setprio(0);

    asm volatile("s_waitcnt vmcnt(0)" ::: "memory");
    __builtin_amdgcn_s_barrier();

    if (lastB) {
      store_o(acc, acc5, q0 + 16 * w, g, lm, Y, b, h);
      q0 = p * 64;
      qg = q0 + w * 16 + lm;
      qf0 = *(const half8*)(Qb + (size_t)(q0 + w * 16 + lm) * HDim + g * 8);
      qf1 = *(const half8*)(Qb + (size_t)(q0 + w * 16 + lm) * HDim + 32 + g * 8);
      acc5 = (floatx4)0.f;
#pragma unroll
      for (int ng = 0; ng < 4; ++ng) acc[ng] = (floatx4)0.f;
    }
  }

  store_o(acc, acc5, q0 + 16 * w, g, lm, Y, b, h);
}

// ---------------- launcher ----------------
extern "C" void kernel_launch(void* const* d_in, const int* in_sizes, int n_in,
                              void* d_out, int out_size, void* d_ws, size_t ws_size,
                              hipStream_t stream)
{
  const float* x      = (const float*)d_in[0];
  const float* W_attn = (const float*)d_in[1];
  const float* W_proj = (const float*)d_in[2];
  float* out = (float*)d_out;

  char* ws = (char*)d_ws;
  f16* xh  = (f16*)(ws);
  f16* wAh = (f16*)(ws + (size_t)(16u << 20));
  f16* wPh = (f16*)(ws + (size_t)(22u << 20));
  f16* Qh  = (f16*)(ws + (size_t)(24u << 20));
  f16* Kh  = (f16*)(ws + (size_t)(40u << 20));
  f16* Vth = (f16*)(ws + (size_t)(56u << 20));  // V^T [B,H,HD,T]
  f16* yh  = xh;

  constexpr int ntot = (Mtok * Cdim + 3 * Cdim * Cdim + Cdim * Cdim) / 4;
  cvt3_kernel<<<(ntot + 255) / 256, 256, 0, stream>>>(x, W_attn, W_proj, xh, wAh, wPh);

  qk8p_kernel<<<dim3(256), 512, 0, stream>>>(xh, wAh, Qh, Kh);

  vt_kernel<<<dim3(512), 256, 0, stream>>>(xh, wAh + (size_t)2048 * Cdim, Vth);

  attn_kernel<<<dim3(1024), 256, 0, stream>>>(Qh, Kh, Vth, yh);

  proj_kernel<<<dim3(512), 256, 0, stream>>>(yh, wPh, out);
}

// Round 17
// 155.201 us; speedup vs baseline: 1.1171x; 1.0836x over previous
//
#include <hip/hip_runtime.h>

typedef _Float16 f16;
typedef _Float16 half8 __attribute__((ext_vector_type(8)));
typedef _Float16 half4v __attribute__((ext_vector_type(4)));
typedef __fp16 fp16x2 __attribute__((ext_vector_type(2)));
typedef float floatx4 __attribute__((ext_vector_type(4)));
typedef unsigned int uint;

constexpr int Bsz = 4, Tseq = 2048, Cdim = 1024, NH = 16, HDim = 64;
constexpr int Mtok = Bsz * Tseq;      // 8192
constexpr int NQT = Tseq / 64;        // 32 q-tiles
constexpr float QSCALE = 0.18033688f; // 0.125 * log2(e)

#define GLDS16(src, dst) __builtin_amdgcn_global_load_lds( \
    (const __attribute__((address_space(1))) void*)(src),  \
    (__attribute__((address_space(3))) void*)(dst), 16, 0, 0)

__device__ __forceinline__ float fexp2(float x) { return __builtin_amdgcn_exp2f(x); }
__device__ __forceinline__ uint pkrtz(float a, float b) {
  fp16x2 h = __builtin_amdgcn_cvt_pkrtz(a, b);
  return __builtin_bit_cast(uint, h);
}
#define MFMA16(a, b, c) __builtin_amdgcn_mfma_f32_16x16x32_f16((a), (b), (c), 0, 0, 0)

// ---------------- fused f32 -> f16 conversion (x, W_attn, W_proj) ----------------
__global__ void cvt3_kernel(const float* __restrict__ x, const float* __restrict__ wa,
                            const float* __restrict__ wp,
                            f16* __restrict__ xh, f16* __restrict__ wah, f16* __restrict__ wph) {
  constexpr int nx = Mtok * Cdim, nwa = 3 * Cdim * Cdim, nwp = Cdim * Cdim;
  int i = (blockIdx.x * blockDim.x + threadIdx.x) * 4;
  const float* src; f16* dst; int off;
  if (i < nx)            { src = x;  dst = xh;  off = i; }
  else if (i < nx + nwa) { src = wa; dst = wah; off = i - nx; }
  else                   { src = wp; dst = wph; off = i - nx - nwa; }
  float4 v = *(const float4*)(src + off);
  half4v o;
  o[0] = (f16)v.x; o[1] = (f16)v.y; o[2] = (f16)v.z; o[3] = (f16)v.w;
  *(half4v*)(dst + off) = o;
}

// ============ qk projection: 256x256 tile, 8-wave, 8-phase (R15, verified) ============
__global__ __launch_bounds__(512, 2)
void qk8p_kernel(const f16* __restrict__ X, const f16* __restrict__ W,
                 f16* __restrict__ q_out, f16* __restrict__ k_out)
{
  __shared__ __align__(16) char smem[131072];
  constexpr int K = 1024, NT = 16;
  const int sbid = (blockIdx.x & 7) * 32 + (blockIdx.x >> 3);
  const int bm = sbid >> 3, bn = sbid & 7;
  const int m0 = bm * 256, n0 = bn * 256;
  const int tid = threadIdx.x, w = tid >> 6, lane = tid & 63;
  const int wr = w >> 2, wc = w & 3;
  const int g = lane >> 4, lm = lane & 15;

  const int grow = lane >> 3;
  const int cg = (lane & 7) ^ grow;

  auto stage_half = [&](int op, int t, int h) {
    const f16* src = op ? W : X;
    char* base = smem + op * 65536 + (t & 1) * 32768 + h * 16384;
    const int rbase = (op ? n0 : m0) + h * 128;
#pragma unroll
    for (int r2 = 0; r2 < 2; ++r2) {
      int row = rbase + r2 * 64 + w * 8 + grow;
      GLDS16(src + (size_t)row * K + t * 64 + cg * 8,
             base + (r2 * 64 + w * 8) * 128);
    }
  };

  floatx4 acc[8][4];
#pragma unroll
  for (int i = 0; i < 8; ++i)
#pragma unroll
    for (int j = 0; j < 4; ++j) acc[i][j] = (floatx4)0.0f;

  const int sw = lm & 7;
  const char* S = smem;
  const int Abase = wr * 16384 + lm * 128;
  const int Bbase = 65536 + (wc >> 1) * 16384 + ((wc & 1) * 64 + lm) * 128;

  half8 a0[4][2], a1[4][2], b0[2][2], b1[2][2];

  stage_half(0, 0, 0); stage_half(0, 0, 1);
  stage_half(1, 0, 0); stage_half(1, 0, 1);
  stage_half(1, 1, 0); stage_half(1, 1, 1);

#pragma unroll 2
  for (int t = 0; t < NT; ++t) {
    const int par = (t & 1) * 32768;

    if (t == NT - 1) { asm volatile("s_waitcnt vmcnt(0)" ::: "memory"); }
    else             { asm volatile("s_waitcnt vmcnt(4)" ::: "memory"); }
    __builtin_amdgcn_s_barrier();
#pragma unroll
    for (int i = 0; i < 4; ++i)
#pragma unroll
      for (int kk = 0; kk < 2; ++kk)
        a0[i][kk] = *(const half8*)(S + par + Abase + i * 2048 + 16 * ((kk * 4 + g) ^ sw));
#pragma unroll
    for (int j = 0; j < 2; ++j)
#pragma unroll
      for (int kk = 0; kk < 2; ++kk)
        b0[j][kk] = *(const half8*)(S + par + Bbase + j * 2048 + 16 * ((kk * 4 + g) ^ sw));
    if (t + 1 < NT) stage_half(0, t + 1, 0);
    asm volatile("s_waitcnt lgkmcnt(0)" ::: "memory");
    __builtin_amdgcn_sched_barrier(0);
    __builtin_amdgcn_s_setprio(1);
#pragma unroll
    for (int i = 0; i < 4; ++i)
#pragma unroll
      for (int j = 0; j < 2; ++j)
#pragma unroll
        for (int kk = 0; kk < 2; ++kk)
          acc[i][j] = MFMA16(a0[i][kk], b0[j][kk], acc[i][j]);
    __builtin_amdgcn_s_setprio(0);

    __builtin_amdgcn_s_barrier();
#pragma unroll
    for (int j = 0; j < 2; ++j)
#pragma unroll
      for (int kk = 0; kk < 2; ++kk)
        b1[j][kk] = *(const half8*)(S + par + Bbase + (j + 2) * 2048 + 16 * ((kk * 4 + g) ^ sw));
    if (t + 1 < NT) stage_half(0, t + 1, 1);
    asm volatile("s_waitcnt lgkmcnt(0)" ::: "memory");
    __builtin_amdgcn_sched_barrier(0);
    __builtin_amdgcn_s_setprio(1);
#pragma unroll
    for (int i = 0; i < 4; ++i)
#pragma unroll
      for (int j = 0; j < 2; ++j)
#pragma unroll
        for (int kk = 0; kk < 2; ++kk)
          acc[i][j + 2] = MFMA16(a0[i][kk], b1[j][kk], acc[i][j + 2]);
    __builtin_amdgcn_s_setprio(0);

    __builtin_amdgcn_s_barrier();
#pragma unroll
    for (int i = 0; i < 4; ++i)
#pragma unroll
      for (int kk = 0; kk < 2; ++kk)
        a1[i][kk] = *(const half8*)(S + par + Abase + (i + 4) * 2048 + 16 * ((kk * 4 + g) ^ sw));
    if (t + 2 < NT) stage_half(1, t + 2, 0);
    asm volatile("s_waitcnt lgkmcnt(0)" ::: "memory");
    __builtin_amdgcn_sched_barrier(0);
    __builtin_amdgcn_s_setprio(1);
#pragma unroll
    for (int i = 0; i < 4; ++i)
#pragma unroll
      for (int j = 0; j < 2; ++j)
#pragma unroll
        for (int kk = 0; kk < 2; ++kk)
          acc[i + 4][j + 2] = MFMA16(a1[i][kk], b1[j][kk], acc[i + 4][j + 2]);
    __builtin_amdgcn_s_setprio(0);

    __builtin_amdgcn_s_barrier();
    if (t + 2 < NT) stage_half(1, t + 2, 1);
    __builtin_amdgcn_s_setprio(1);
#pragma unroll
    for (int i = 0; i < 4; ++i)
#pragma unroll
      for (int j = 0; j < 2; ++j)
#pragma unroll
        for (int kk = 0; kk < 2; ++kk)
          acc[i + 4][j] = MFMA16(a1[i][kk], b0[j][kk], acc[i + 4][j]);
    __builtin_amdgcn_s_setprio(0);
  }

#pragma unroll
  for (int i = 0; i < 8; ++i) {
#pragma unroll
    for (int j = 0; j < 4; ++j) {
#pragma unroll
      for (int r = 0; r < 4; ++r) {
        int m = m0 + wr * 128 + i * 16 + 4 * g + r;
        int n = n0 + wc * 64 + j * 16 + lm;
        float v = acc[i][j][r];
        int which = n >> 10;
        int inner = n & 1023;
        int h = inner >> 6, hd = inner & 63;
        int b = m >> 11, t = m & 2047;
        if (which == 0) {
          v *= QSCALE;
          q_out[(((size_t)(b * NH + h)) * Tseq + t) * HDim + hd] = (f16)v;
        } else {
          k_out[(((size_t)(b * NH + h)) * Tseq + t) * HDim + hd] = (f16)v;
        }
      }
    }
  }
}

// ============ 128x256-tile 8-phase GEMM body (vt / proj) ============
// 8 waves (2x4), 64x64 out each; BK=64, NT=16. LDS 96KB: A dbuf 2x16KB @0,
// B dbuf 2x32KB @32768. Phases: P0 A0B0 +stageA(t+1,h0); P1 A0B1 +stageA(t+1,h1);
// P2 A1B1 +stageB(t+2,h0); P3 A1B0 +stageB(t+2,h1). vmcnt(4) at P0 (B(t+1) in
// flight), vmcnt(0) at last tile. Same race invariants as qk8p (all B[t] reads
// retire before the P2 barrier; stage_A targets opposite parity).
// EPI 1: proj f32 out[m*Cdim+n] (m=token, n=c). EPI 2: V^T f16 (m=W_v row, n=token).
template<int EPI>
__device__ __forceinline__ void g8p_body(char* smem,
    const f16* __restrict__ A, const f16* __restrict__ B,
    float* __restrict__ outF, f16* __restrict__ v_out,
    int bm, int bn)
{
  constexpr int K = 1024, NT = 16;
  const int m0 = bm * 128, n0 = bn * 256;
  const int tid = threadIdx.x, w = tid >> 6, lane = tid & 63;
  const int wr = w >> 2, wc = w & 3;
  const int g = lane >> 4, lm = lane & 15;
  const int grow = lane >> 3;
  const int cg = (lane & 7) ^ grow;

  auto stage_A = [&](int t, int h) {
    int row = m0 + h * 64 + w * 8 + grow;
    GLDS16(A + (size_t)row * K + t * 64 + cg * 8,
           smem + (t & 1) * 16384 + (h * 64 + w * 8) * 128);
  };
  auto stage_B = [&](int t, int h) {
#pragma unroll
    for (int r2 = 0; r2 < 2; ++r2) {
      int row = n0 + h * 128 + r2 * 64 + w * 8 + grow;
      GLDS16(B + (size_t)row * K + t * 64 + cg * 8,
             smem + 32768 + (t & 1) * 32768 + (h * 128 + r2 * 64 + w * 8) * 128);
    }
  };

  floatx4 acc[4][4];
#pragma unroll
  for (int i = 0; i < 4; ++i)
#pragma unroll
    for (int j = 0; j < 4; ++j) acc[i][j] = (floatx4)0.0f;

  const int sw = lm & 7;
  const char* S = smem;
  const int Abase = (wr * 64 + lm) * 128;
  const int Bbase = 32768 + (wc * 64 + lm) * 128;

  half8 a0[2][2], a1[2][2], b0[2][2], b1[2][2];

  stage_A(0, 0); stage_A(0, 1);
  stage_B(0, 0); stage_B(0, 1);
  stage_B(1, 0); stage_B(1, 1);

#pragma unroll 2
  for (int t = 0; t < NT; ++t) {
    const int parA = (t & 1) * 16384;
    const int parB = (t & 1) * 32768;

    // P0: A0 x B0
    if (t == NT - 1) { asm volatile("s_waitcnt vmcnt(0)" ::: "memory"); }
    else             { asm volatile("s_waitcnt vmcnt(4)" ::: "memory"); }
    __builtin_amdgcn_s_barrier();
#pragma unroll
    for (int i = 0; i < 2; ++i)
#pragma unroll
      for (int kk = 0; kk < 2; ++kk)
        a0[i][kk] = *(const half8*)(S + parA + Abase + i * 2048 + 16 * ((kk * 4 + g) ^ sw));
#pragma unroll
    for (int j = 0; j < 2; ++j)
#pragma unroll
      for (int kk = 0; kk < 2; ++kk)
        b0[j][kk] = *(const half8*)(S + parB + Bbase + j * 2048 + 16 * ((kk * 4 + g) ^ sw));
    if (t + 1 < NT) stage_A(t + 1, 0);
    asm volatile("s_waitcnt lgkmcnt(0)" ::: "memory");
    __builtin_amdgcn_sched_barrier(0);
    __builtin_amdgcn_s_setprio(1);
#pragma unroll
    for (int i = 0; i < 2; ++i)
#pragma unroll
      for (int j = 0; j < 2; ++j)
#pragma unroll
        for (int kk = 0; kk < 2; ++kk)
          acc[i][j] = MFMA16(a0[i][kk], b0[j][kk], acc[i][j]);
    __builtin_amdgcn_s_setprio(0);

    // P1: A0 x B1
    __builtin_amdgcn_s_barrier();
#pragma unroll
    for (int j = 0; j < 2; ++j)
#pragma unroll
      for (int kk = 0; kk < 2; ++kk)
        b1[j][kk] = *(const half8*)(S + parB + Bbase + (j + 2) * 2048 + 16 * ((kk * 4 + g) ^ sw));
    if (t + 1 < NT) stage_A(t + 1, 1);
    asm volatile("s_waitcnt lgkmcnt(0)" ::: "memory");
    __builtin_amdgcn_sched_barrier(0);
    __builtin_amdgcn_s_setprio(1);
#pragma unroll
    for (int i = 0; i < 2; ++i)
#pragma unroll
      for (int j = 0; j < 2; ++j)
#pragma unroll
        for (int kk = 0; kk < 2; ++kk)
          acc[i][j + 2] = MFMA16(a0[i][kk], b1[j][kk], acc[i][j + 2]);
    __builtin_amdgcn_s_setprio(0);

    // P2: A1 x B1
    __builtin_amdgcn_s_barrier();
#pragma unroll
    for (int i = 0; i < 2; ++i)
#pragma unroll
      for (int kk = 0; kk < 2; ++kk)
        a1[i][kk] = *(const half8*)(S + parA + Abase + (i + 2) * 2048 + 16 * ((kk * 4 + g) ^ sw));
    if (t + 2 < NT) stage_B(t + 2, 0);
    asm volatile("s_waitcnt lgkmcnt(0)" ::: "memory");
    __builtin_amdgcn_sched_barrier(0);
    __builtin_amdgcn_s_setprio(1);
#pragma unroll
    for (int i = 0; i < 2; ++i)
#pragma unroll
      for (int j = 0; j < 2; ++j)
#pragma unroll
        for (int kk = 0; kk < 2; ++kk)
          acc[i + 2][j + 2] = MFMA16(a1[i][kk], b1[j][kk], acc[i + 2][j + 2]);
    __builtin_amdgcn_s_setprio(0);

    // P3: A1 x B0 (no new reads)
    __builtin_amdgcn_s_barrier();
    if (t + 2 < NT) stage_B(t + 2, 1);
    __builtin_amdgcn_s_setprio(1);
#pragma unroll
    for (int i = 0; i < 2; ++i)
#pragma unroll
      for (int j = 0; j < 2; ++j)
#pragma unroll
        for (int kk = 0; kk < 2; ++kk)
          acc[i + 2][j] = MFMA16(a1[i][kk], b0[j][kk], acc[i + 2][j]);
    __builtin_amdgcn_s_setprio(0);
  }

#pragma unroll
  for (int i = 0; i < 4; ++i) {
#pragma unroll
    for (int j = 0; j < 4; ++j) {
#pragma unroll
      for (int r = 0; r < 4; ++r) {
        int m = m0 + wr * 64 + i * 16 + 4 * g + r;
        int n = n0 + wc * 64 + j * 16 + lm;
        float v = acc[i][j][r];
        if constexpr (EPI == 1) {
          outF[(size_t)m * Cdim + n] = v;
        } else {
          int h = m >> 6, hd = m & 63;
          int b = n >> 11, tt = n & 2047;
          v_out[(((size_t)(b * NH + h)) * HDim + hd) * Tseq + tt] = (f16)v;
        }
      }
    }
  }
}

// V^T: A=W_v (8 bm), B=x (32 bn); per XCD: 4 bn x all bm (L2 set ~4MB)
__global__ __launch_bounds__(512, 2)
void vt8p_kernel(const f16* __restrict__ xh, const f16* __restrict__ wVh, f16* __restrict__ Vth) {
  __shared__ __align__(16) char smem[98304];
  const int x = blockIdx.x & 7, q = blockIdx.x >> 3;   // 256 blocks
  int bn = x * 4 + (q >> 3);
  int bm = q & 7;
  g8p_body<2>(smem, wVh, xh, nullptr, Vth, bm, bn);
}

// proj: A=y (64 bm), B=W_p (4 bn); per XCD: 8 bm x all bn
__global__ __launch_bounds__(512, 2)
void proj8p_kernel(const f16* __restrict__ yh, const f16* __restrict__ wPh, float* __restrict__ out) {
  __shared__ __align__(16) char smem[98304];
  const int x = blockIdx.x & 7, q = blockIdx.x >> 3;   // 256 blocks
  int bm = x * 8 + (q >> 2);
  int bn = q & 3;
  g8p_body<1>(smem, yh, wPh, out, nullptr, bm, bn);
}

// ---------------- causal flash attention (R16 form, unchanged) ----------------
__device__ __forceinline__ void softmax_tile(floatx4* s,
                                             bool diag, int j0, int qg, char* pwrow, int g, int lm) {
  if (diag) {
#pragma unroll
    for (int nf = 0; nf < 4; ++nf)
#pragma unroll
      for (int r = 0; r < 4; ++r)
        if (j0 + nf * 16 + 4 * g + r > qg) s[nf][r] = -1e30f;
  }
#pragma unroll
  for (int nf = 0; nf < 4; ++nf) {
    float p0 = fexp2(s[nf][0]), p1 = fexp2(s[nf][1]);
    float p2 = fexp2(s[nf][2]), p3 = fexp2(s[nf][3]);
    uint lo = pkrtz(p0, p1), hi = pkrtz(p2, p3);
    int slot = 2 * nf + (g >> 1);
    uint2 u; u.x = lo; u.y = hi;
    *(uint2*)(pwrow + 16 * (slot ^ (lm & 7)) + 8 * (g & 1)) = u;
  }
}

__device__ __forceinline__ void store_o(const floatx4* acc, const floatx4 l5, int q0w,
                                        int g, int lm, f16* __restrict__ Y, int b, int h) {
#pragma unroll
  for (int r = 0; r < 4; ++r) {
    float inv = 1.0f / l5[r];
    int t = q0w + 4 * g + r;
    size_t base = ((size_t)(b * Tseq + t)) * Cdim + h * HDim;
#pragma unroll
    for (int ng = 0; ng < 4; ++ng)
      Y[base + ng * 16 + lm] = (f16)(acc[ng][r] * inv);
  }
}

__global__ __launch_bounds__(256)
void attn_kernel(const f16* __restrict__ Q, const f16* __restrict__ Kg,
                 const f16* __restrict__ Vt, f16* __restrict__ Y)
{
  __shared__ __align__(16) char smem[40960];
  int wg = blockIdx.x;
  int lin = (wg & 7) * 128 + (wg >> 3);
  const int p  = lin & 15;
  const int bh = lin >> 4;
  const int itB = NQT - p;
  const f16* Qb  = Q  + (size_t)bh * Tseq * HDim;
  const f16* Kb  = Kg + (size_t)bh * Tseq * HDim;
  const f16* Vtb = Vt + (size_t)bh * HDim * Tseq;

  const int tid = threadIdx.x, w = tid >> 6, lane = tid & 63;
  const int g = lane >> 4, lm = lane & 15;
  char* pwrow = smem + 32768 + w * 2048 + lm * 128;
  const int b = bh >> 4, h = bh & 15;

  half8 ones;
#pragma unroll
  for (int i = 0; i < 8; ++i) ones[i] = (f16)1.0f;

  int q0 = (NQT - 1 - p) * 64;
  int qg = q0 + w * 16 + lm;
  half8 qf0 = *(const half8*)(Qb + (size_t)(q0 + w * 16 + lm) * HDim + g * 8);
  half8 qf1 = *(const half8*)(Qb + (size_t)(q0 + w * 16 + lm) * HDim + 32 + g * 8);

  floatx4 acc[4], acc5;
  acc5 = (floatx4)0.f;
#pragma unroll
  for (int ng = 0; ng < 4; ++ng) acc[ng] = (floatx4)0.f;

  const int srow = w * 8 + (lane >> 3);
  const int sslot = lane & 7;

  auto stage = [&](int j0s, int buf) {
#pragma unroll
    for (int t = 0; t < 2; ++t) {
      int row = srow + t * 32;
      int cg = sslot ^ (row & 7);
      GLDS16(Kb + (size_t)(j0s + row) * HDim + cg * 8,
             smem + buf * 8192 + (w * 8 + t * 32) * 128);
      GLDS16(Vtb + (size_t)row * Tseq + j0s + cg * 8,
             smem + 16384 + buf * 8192 + (w * 8 + t * 32) * 128);
    }
  };

  stage(0, 0);
  asm volatile("s_waitcnt vmcnt(0)" ::: "memory");
  __builtin_amdgcn_s_barrier();

  for (int it = 0; it < NQT + 1; ++it) {
    const bool lastB = (it == itB - 1);
    const bool last  = (it == NQT);
    const int jt = (it < itB) ? it : it - itB;
    const int j0 = jt * 64;

    if (!last) {
      const int itn = it + 1;
      const int jtn = (itn < itB) ? itn : itn - itB;
      stage(jtn * 64, itn & 1);
    }

    char* kb   = smem + (it & 1) * 8192;
    char* vbuf = smem + 16384 + (it & 1) * 8192;

    floatx4 s[4];
    __builtin_amdgcn_s_setprio(1);
#pragma unroll
    for (int nf = 0; nf < 4; ++nf) {
      half8 kf0 = *(const half8*)(kb + (nf * 16 + lm) * 128 + 16 * ((g)     ^ (lm & 7)));
      half8 kf1 = *(const half8*)(kb + (nf * 16 + lm) * 128 + 16 * ((4 + g) ^ (lm & 7)));
      s[nf] = MFMA16(kf0, qf0, (floatx4)0.f);
      s[nf] = MFMA16(kf1, qf1, s[nf]);
    }
    __builtin_amdgcn_s_setprio(0);

    softmax_tile(s, lastB || last, j0, qg, pwrow, g, lm);
    half8 pa0 = *(const half8*)(pwrow + 16 * ((g)     ^ (lm & 7)));
    half8 pa1 = *(const half8*)(pwrow + 16 * ((4 + g) ^ (lm & 7)));

    __builtin_amdgcn_s_setprio(1);
    acc5 = MFMA16(pa0, ones, acc5);
    acc5 = MFMA16(pa1, ones, acc5);
#pragma unroll
    for (int c = 0; c < 2; ++c)
#pragma unroll
      for (int ng = 0; ng < 4; ++ng) {
        half8 vbf = *(const half8*)(vbuf + (ng * 16 + lm) * 128 + 16 * ((4 * c + g) ^ (lm & 7)));
        acc[ng] = MFMA16(c ? pa1 : pa0, vbf, acc[ng]);
      }
    __builtin_amdgcn_s_setprio(0);

    asm volatile("s_waitcnt vmcnt(0)" ::: "memory");
    __builtin_amdgcn_s_barrier();

    if (lastB) {
      store_o(acc, acc5, q0 + 16 * w, g, lm, Y, b, h);
      q0 = p * 64;
      qg = q0 + w * 16 + lm;
      qf0 = *(const half8*)(Qb + (size_t)(q0 + w * 16 + lm) * HDim + g * 8);
      qf1 = *(const half8*)(Qb + (size_t)(q0 + w * 16 + lm) * HDim + 32 + g * 8);
      acc5 = (floatx4)0.f;
#pragma unroll
      for (int ng = 0; ng < 4; ++ng) acc[ng] = (floatx4)0.f;
    }
  }

  store_o(acc, acc5, q0 + 16 * w, g, lm, Y, b, h);
}

// ---------------- launcher ----------------
extern "C" void kernel_launch(void* const* d_in, const int* in_sizes, int n_in,
                              void* d_out, int out_size, void* d_ws, size_t ws_size,
                              hipStream_t stream)
{
  const float* x      = (const float*)d_in[0];
  const float* W_attn = (const float*)d_in[1];
  const float* W_proj = (const float*)d_in[2];
  float* out = (float*)d_out;

  char* ws = (char*)d_ws;
  f16* xh  = (f16*)(ws);
  f16* wAh = (f16*)(ws + (size_t)(16u << 20));
  f16* wPh = (f16*)(ws + (size_t)(22u << 20));
  f16* Qh  = (f16*)(ws + (size_t)(24u << 20));
  f16* Kh  = (f16*)(ws + (size_t)(40u << 20));
  f16* Vth = (f16*)(ws + (size_t)(56u << 20));  // V^T [B,H,HD,T]
  f16* yh  = xh;

  constexpr int ntot = (Mtok * Cdim + 3 * Cdim * Cdim + Cdim * Cdim) / 4;
  cvt3_kernel<<<(ntot + 255) / 256, 256, 0, stream>>>(x, W_attn, W_proj, xh, wAh, wPh);

  qk8p_kernel<<<dim3(256), 512, 0, stream>>>(xh, wAh, Qh, Kh);

  vt8p_kernel<<<dim3(256), 512, 0, stream>>>(xh, wAh + (size_t)2048 * Cdim, Vth);

  attn_kernel<<<dim3(1024), 256, 0, stream>>>(Qh, Kh, Vth, yh);

  proj8p_kernel<<<dim3(256), 512, 0, stream>>>(yh, wPh, out);
}

// Round 18
// 153.650 us; speedup vs baseline: 1.1284x; 1.0101x over previous
//
#include <hip/hip_runtime.h>

typedef _Float16 f16;
typedef _Float16 half8 __attribute__((ext_vector_type(8)));
typedef _Float16 half4v __attribute__((ext_vector_type(4)));
typedef __fp16 fp16x2 __attribute__((ext_vector_type(2)));
typedef float floatx4 __attribute__((ext_vector_type(4)));
typedef unsigned int uint;

constexpr int Bsz = 4, Tseq = 2048, Cdim = 1024, NH = 16, HDim = 64;
constexpr int Mtok = Bsz * Tseq;      // 8192
constexpr int NQT = Tseq / 64;        // 32 q-tiles
constexpr float QSCALE = 0.18033688f; // 0.125 * log2(e)

#define GLDS16(src, dst) __builtin_amdgcn_global_load_lds( \
    (const __attribute__((address_space(1))) void*)(src),  \
    (__attribute__((address_space(3))) void*)(dst), 16, 0, 0)

__device__ __forceinline__ float fexp2(float x) { return __builtin_amdgcn_exp2f(x); }
__device__ __forceinline__ uint pkrtz(float a, float b) {
  fp16x2 h = __builtin_amdgcn_cvt_pkrtz(a, b);
  return __builtin_bit_cast(uint, h);
}
#define MFMA16(a, b, c) __builtin_amdgcn_mfma_f32_16x16x32_f16((a), (b), (c), 0, 0, 0)

// ---------------- fused f32 -> f16 conversion (x, W_attn, W_proj) ----------------
__global__ void cvt3_kernel(const float* __restrict__ x, const float* __restrict__ wa,
                            const float* __restrict__ wp,
                            f16* __restrict__ xh, f16* __restrict__ wah, f16* __restrict__ wph) {
  constexpr int nx = Mtok * Cdim, nwa = 3 * Cdim * Cdim, nwp = Cdim * Cdim;
  int i = (blockIdx.x * blockDim.x + threadIdx.x) * 4;
  const float* src; f16* dst; int off;
  if (i < nx)            { src = x;  dst = xh;  off = i; }
  else if (i < nx + nwa) { src = wa; dst = wah; off = i - nx; }
  else                   { src = wp; dst = wph; off = i - nx - nwa; }
  float4 v = *(const float4*)(src + off);
  half4v o;
  o[0] = (f16)v.x; o[1] = (f16)v.y; o[2] = (f16)v.z; o[3] = (f16)v.w;
  *(half4v*)(dst + off) = o;
}

// ============ qk projection body: 256x256 tile, 8-wave, 8-phase (R15, verified) ====
__device__ __forceinline__ void qk8p_body(char* smem,
    const f16* __restrict__ X, const f16* __restrict__ W,
    f16* __restrict__ q_out, f16* __restrict__ k_out, int sbid)
{
  constexpr int K = 1024, NT = 16;
  const int bm = sbid >> 3, bn = sbid & 7;
  const int m0 = bm * 256, n0 = bn * 256;
  const int tid = threadIdx.x, w = tid >> 6, lane = tid & 63;
  const int wr = w >> 2, wc = w & 3;
  const int g = lane >> 4, lm = lane & 15;

  const int grow = lane >> 3;
  const int cg = (lane & 7) ^ grow;

  auto stage_half = [&](int op, int t, int h) {
    const f16* src = op ? W : X;
    char* base = smem + op * 65536 + (t & 1) * 32768 + h * 16384;
    const int rbase = (op ? n0 : m0) + h * 128;
#pragma unroll
    for (int r2 = 0; r2 < 2; ++r2) {
      int row = rbase + r2 * 64 + w * 8 + grow;
      GLDS16(src + (size_t)row * K + t * 64 + cg * 8,
             base + (r2 * 64 + w * 8) * 128);
    }
  };

  floatx4 acc[8][4];
#pragma unroll
  for (int i = 0; i < 8; ++i)
#pragma unroll
    for (int j = 0; j < 4; ++j) acc[i][j] = (floatx4)0.0f;

  const int sw = lm & 7;
  const char* S = smem;
  const int Abase = wr * 16384 + lm * 128;
  const int Bbase = 65536 + (wc >> 1) * 16384 + ((wc & 1) * 64 + lm) * 128;

  half8 a0[4][2], a1[4][2], b0[2][2], b1[2][2];

  stage_half(0, 0, 0); stage_half(0, 0, 1);
  stage_half(1, 0, 0); stage_half(1, 0, 1);
  stage_half(1, 1, 0); stage_half(1, 1, 1);

#pragma unroll 2
  for (int t = 0; t < NT; ++t) {
    const int par = (t & 1) * 32768;

    if (t == NT - 1) { asm volatile("s_waitcnt vmcnt(0)" ::: "memory"); }
    else             { asm volatile("s_waitcnt vmcnt(4)" ::: "memory"); }
    __builtin_amdgcn_s_barrier();
#pragma unroll
    for (int i = 0; i < 4; ++i)
#pragma unroll
      for (int kk = 0; kk < 2; ++kk)
        a0[i][kk] = *(const half8*)(S + par + Abase + i * 2048 + 16 * ((kk * 4 + g) ^ sw));
#pragma unroll
    for (int j = 0; j < 2; ++j)
#pragma unroll
      for (int kk = 0; kk < 2; ++kk)
        b0[j][kk] = *(const half8*)(S + par + Bbase + j * 2048 + 16 * ((kk * 4 + g) ^ sw));
    if (t + 1 < NT) stage_half(0, t + 1, 0);
    asm volatile("s_waitcnt lgkmcnt(0)" ::: "memory");
    __builtin_amdgcn_sched_barrier(0);
    __builtin_amdgcn_s_setprio(1);
#pragma unroll
    for (int i = 0; i < 4; ++i)
#pragma unroll
      for (int j = 0; j < 2; ++j)
#pragma unroll
        for (int kk = 0; kk < 2; ++kk)
          acc[i][j] = MFMA16(a0[i][kk], b0[j][kk], acc[i][j]);
    __builtin_amdgcn_s_setprio(0);

    __builtin_amdgcn_s_barrier();
#pragma unroll
    for (int j = 0; j < 2; ++j)
#pragma unroll
      for (int kk = 0; kk < 2; ++kk)
        b1[j][kk] = *(const half8*)(S + par + Bbase + (j + 2) * 2048 + 16 * ((kk * 4 + g) ^ sw));
    if (t + 1 < NT) stage_half(0, t + 1, 1);
    asm volatile("s_waitcnt lgkmcnt(0)" ::: "memory");
    __builtin_amdgcn_sched_barrier(0);
    __builtin_amdgcn_s_setprio(1);
#pragma unroll
    for (int i = 0; i < 4; ++i)
#pragma unroll
      for (int j = 0; j < 2; ++j)
#pragma unroll
        for (int kk = 0; kk < 2; ++kk)
          acc[i][j + 2] = MFMA16(a0[i][kk], b1[j][kk], acc[i][j + 2]);
    __builtin_amdgcn_s_setprio(0);

    __builtin_amdgcn_s_barrier();
#pragma unroll
    for (int i = 0; i < 4; ++i)
#pragma unroll
      for (int kk = 0; kk < 2; ++kk)
        a1[i][kk] = *(const half8*)(S + par + Abase + (i + 4) * 2048 + 16 * ((kk * 4 + g) ^ sw));
    if (t + 2 < NT) stage_half(1, t + 2, 0);
    asm volatile("s_waitcnt lgkmcnt(0)" ::: "memory");
    __builtin_amdgcn_sched_barrier(0);
    __builtin_amdgcn_s_setprio(1);
#pragma unroll
    for (int i = 0; i < 4; ++i)
#pragma unroll
      for (int j = 0; j < 2; ++j)
#pragma unroll
        for (int kk = 0; kk < 2; ++kk)
          acc[i + 4][j + 2] = MFMA16(a1[i][kk], b1[j][kk], acc[i + 4][j + 2]);
    __builtin_amdgcn_s_setprio(0);

    __builtin_amdgcn_s_barrier();
    if (t + 2 < NT) stage_half(1, t + 2, 1);
    __builtin_amdgcn_s_setprio(1);
#pragma unroll
    for (int i = 0; i < 4; ++i)
#pragma unroll
      for (int j = 0; j < 2; ++j)
#pragma unroll
        for (int kk = 0; kk < 2; ++kk)
          acc[i + 4][j] = MFMA16(a1[i][kk], b0[j][kk], acc[i + 4][j]);
    __builtin_amdgcn_s_setprio(0);
  }

#pragma unroll
  for (int i = 0; i < 8; ++i) {
#pragma unroll
    for (int j = 0; j < 4; ++j) {
#pragma unroll
      for (int r = 0; r < 4; ++r) {
        int m = m0 + wr * 128 + i * 16 + 4 * g + r;
        int n = n0 + wc * 64 + j * 16 + lm;
        float v = acc[i][j][r];
        int which = n >> 10;
        int inner = n & 1023;
        int h = inner >> 6, hd = inner & 63;
        int b = m >> 11, t = m & 2047;
        if (which == 0) {
          v *= QSCALE;
          q_out[(((size_t)(b * NH + h)) * Tseq + t) * HDim + hd] = (f16)v;
        } else {
          k_out[(((size_t)(b * NH + h)) * Tseq + t) * HDim + hd] = (f16)v;
        }
      }
    }
  }
}

// ============ 128x256-tile 8-phase GEMM body (vt / proj) — R17, verified ============
template<int EPI>
__device__ __forceinline__ void g8p_body(char* smem,
    const f16* __restrict__ A, const f16* __restrict__ B,
    float* __restrict__ outF, f16* __restrict__ v_out,
    int bm, int bn)
{
  constexpr int K = 1024, NT = 16;
  const int m0 = bm * 128, n0 = bn * 256;
  const int tid = threadIdx.x, w = tid >> 6, lane = tid & 63;
  const int wr = w >> 2, wc = w & 3;
  const int g = lane >> 4, lm = lane & 15;
  const int grow = lane >> 3;
  const int cg = (lane & 7) ^ grow;

  auto stage_A = [&](int t, int h) {
    int row = m0 + h * 64 + w * 8 + grow;
    GLDS16(A + (size_t)row * K + t * 64 + cg * 8,
           smem + (t & 1) * 16384 + (h * 64 + w * 8) * 128);
  };
  auto stage_B = [&](int t, int h) {
#pragma unroll
    for (int r2 = 0; r2 < 2; ++r2) {
      int row = n0 + h * 128 + r2 * 64 + w * 8 + grow;
      GLDS16(B + (size_t)row * K + t * 64 + cg * 8,
             smem + 32768 + (t & 1) * 32768 + (h * 128 + r2 * 64 + w * 8) * 128);
    }
  };

  floatx4 acc[4][4];
#pragma unroll
  for (int i = 0; i < 4; ++i)
#pragma unroll
    for (int j = 0; j < 4; ++j) acc[i][j] = (floatx4)0.0f;

  const int sw = lm & 7;
  const char* S = smem;
  const int Abase = (wr * 64 + lm) * 128;
  const int Bbase = 32768 + (wc * 64 + lm) * 128;

  half8 a0[2][2], a1[2][2], b0[2][2], b1[2][2];

  stage_A(0, 0); stage_A(0, 1);
  stage_B(0, 0); stage_B(0, 1);
  stage_B(1, 0); stage_B(1, 1);

#pragma unroll 2
  for (int t = 0; t < NT; ++t) {
    const int parA = (t & 1) * 16384;
    const int parB = (t & 1) * 32768;

    if (t == NT - 1) { asm volatile("s_waitcnt vmcnt(0)" ::: "memory"); }
    else             { asm volatile("s_waitcnt vmcnt(4)" ::: "memory"); }
    __builtin_amdgcn_s_barrier();
#pragma unroll
    for (int i = 0; i < 2; ++i)
#pragma unroll
      for (int kk = 0; kk < 2; ++kk)
        a0[i][kk] = *(const half8*)(S + parA + Abase + i * 2048 + 16 * ((kk * 4 + g) ^ sw));
#pragma unroll
    for (int j = 0; j < 2; ++j)
#pragma unroll
      for (int kk = 0; kk < 2; ++kk)
        b0[j][kk] = *(const half8*)(S + parB + Bbase + j * 2048 + 16 * ((kk * 4 + g) ^ sw));
    if (t + 1 < NT) stage_A(t + 1, 0);
    asm volatile("s_waitcnt lgkmcnt(0)" ::: "memory");
    __builtin_amdgcn_sched_barrier(0);
    __builtin_amdgcn_s_setprio(1);
#pragma unroll
    for (int i = 0; i < 2; ++i)
#pragma unroll
      for (int j = 0; j < 2; ++j)
#pragma unroll
        for (int kk = 0; kk < 2; ++kk)
          acc[i][j] = MFMA16(a0[i][kk], b0[j][kk], acc[i][j]);
    __builtin_amdgcn_s_setprio(0);

    __builtin_amdgcn_s_barrier();
#pragma unroll
    for (int j = 0; j < 2; ++j)
#pragma unroll
      for (int kk = 0; kk < 2; ++kk)
        b1[j][kk] = *(const half8*)(S + parB + Bbase + (j + 2) * 2048 + 16 * ((kk * 4 + g) ^ sw));
    if (t + 1 < NT) stage_A(t + 1, 1);
    asm volatile("s_waitcnt lgkmcnt(0)" ::: "memory");
    __builtin_amdgcn_sched_barrier(0);
    __builtin_amdgcn_s_setprio(1);
#pragma unroll
    for (int i = 0; i < 2; ++i)
#pragma unroll
      for (int j = 0; j < 2; ++j)
#pragma unroll
        for (int kk = 0; kk < 2; ++kk)
          acc[i][j + 2] = MFMA16(a0[i][kk], b1[j][kk], acc[i][j + 2]);
    __builtin_amdgcn_s_setprio(0);

    __builtin_amdgcn_s_barrier();
#pragma unroll
    for (int i = 0; i < 2; ++i)
#pragma unroll
      for (int kk = 0; kk < 2; ++kk)
        a1[i][kk] = *(const half8*)(S + parA + Abase + (i + 2) * 2048 + 16 * ((kk * 4 + g) ^ sw));
    if (t + 2 < NT) stage_B(t + 2, 0);
    asm volatile("s_waitcnt lgkmcnt(0)" ::: "memory");
    __builtin_amdgcn_sched_barrier(0);
    __builtin_amdgcn_s_setprio(1);
#pragma unroll
    for (int i = 0; i < 2; ++i)
#pragma unroll
      for (int j = 0; j < 2; ++j)
#pragma unroll
        for (int kk = 0; kk < 2; ++kk)
          acc[i + 2][j + 2] = MFMA16(a1[i][kk], b1[j][kk], acc[i + 2][j + 2]);
    __builtin_amdgcn_s_setprio(0);

    __builtin_amdgcn_s_barrier();
    if (t + 2 < NT) stage_B(t + 2, 1);
    __builtin_amdgcn_s_setprio(1);
#pragma unroll
    for (int i = 0; i < 2; ++i)
#pragma unroll
      for (int j = 0; j < 2; ++j)
#pragma unroll
        for (int kk = 0; kk < 2; ++kk)
          acc[i + 2][j] = MFMA16(a1[i][kk], b0[j][kk], acc[i + 2][j]);
    __builtin_amdgcn_s_setprio(0);
  }

#pragma unroll
  for (int i = 0; i < 4; ++i) {
#pragma unroll
    for (int j = 0; j < 4; ++j) {
#pragma unroll
      for (int r = 0; r < 4; ++r) {
        int m = m0 + wr * 64 + i * 16 + 4 * g + r;
        int n = n0 + wc * 64 + j * 16 + lm;
        float v = acc[i][j][r];
        if constexpr (EPI == 1) {
          outF[(size_t)m * Cdim + n] = v;
        } else {
          int h = m >> 6, hd = m & 63;
          int b = n >> 11, tt = n & 2047;
          v_out[(((size_t)(b * NH + h)) * HDim + hd) * Tseq + tt] = (f16)v;
        }
      }
    }
  }
}

// Fused qk + V^T launch: blocks 0..255 qk (128KB LDS), 256..511 vt (uses 96KB).
// Both are 1 block/CU LDS-bound; fusing removes the inter-kernel gap and lets
// CUs finishing qk immediately pull vt blocks (tail overlap).
__global__ __launch_bounds__(512, 2)
void qkvt_kernel(const f16* __restrict__ xh, const f16* __restrict__ wAh,
                 f16* __restrict__ Qh, f16* __restrict__ Kh, f16* __restrict__ Vth) {
  __shared__ __align__(16) char smem[131072];
  if (blockIdx.x < 256) {
    int sbid = (blockIdx.x & 7) * 32 + (blockIdx.x >> 3);
    qk8p_body(smem, xh, wAh, Qh, Kh, sbid);
  } else {
    int bx = blockIdx.x - 256;
    int x = bx & 7, q = bx >> 3;
    int bn = x * 4 + (q >> 3);
    int bm = q & 7;
    g8p_body<2>(smem, wAh + (size_t)2048 * Cdim, xh, nullptr, Vth, bm, bn);
  }
}

__global__ __launch_bounds__(512, 2)
void proj8p_kernel(const f16* __restrict__ yh, const f16* __restrict__ wPh, float* __restrict__ out) {
  __shared__ __align__(16) char smem[98304];
  const int x = blockIdx.x & 7, q = blockIdx.x >> 3;
  int bm = x * 8 + (q >> 2);
  int bn = q & 3;
  g8p_body<1>(smem, yh, wPh, out, nullptr, bm, bn);
}

// ---------------- causal flash attention: affine phase loops ----------------
// Phase B (q-tile 31-p, kv 0..31-p) then phase A (q-tile p, kv 0..p) as separate
// loops with affine jt -> staging addresses strength-reduce to induction adds;
// diag-mask code exists only in the two peeled last iterations. Same buffers,
// barrier schedule (1/iter), divide-only softmax, MFMA l-denominator as R16.
__device__ __forceinline__ void softmax_tile(floatx4* s,
                                             bool diag, int j0, int qg, char* pwrow, int g, int lm) {
  if (diag) {
#pragma unroll
    for (int nf = 0; nf < 4; ++nf)
#pragma unroll
      for (int r = 0; r < 4; ++r)
        if (j0 + nf * 16 + 4 * g + r > qg) s[nf][r] = -1e30f;
  }
#pragma unroll
  for (int nf = 0; nf < 4; ++nf) {
    float p0 = fexp2(s[nf][0]), p1 = fexp2(s[nf][1]);
    float p2 = fexp2(s[nf][2]), p3 = fexp2(s[nf][3]);
    uint lo = pkrtz(p0, p1), hi = pkrtz(p2, p3);
    int slot = 2 * nf + (g >> 1);
    uint2 u; u.x = lo; u.y = hi;
    *(uint2*)(pwrow + 16 * (slot ^ (lm & 7)) + 8 * (g & 1)) = u;
  }
}

__device__ __forceinline__ void store_o(const floatx4* acc, const floatx4 l5, int q0w,
                                        int g, int lm, f16* __restrict__ Y, int b, int h) {
#pragma unroll
  for (int r = 0; r < 4; ++r) {
    float inv = 1.0f / l5[r];
    int t = q0w + 4 * g + r;
    size_t base = ((size_t)(b * Tseq + t)) * Cdim + h * HDim;
#pragma unroll
    for (int ng = 0; ng < 4; ++ng)
      Y[base + ng * 16 + lm] = (f16)(acc[ng][r] * inv);
  }
}

__global__ __launch_bounds__(256)
void attn_kernel(const f16* __restrict__ Q, const f16* __restrict__ Kg,
                 const f16* __restrict__ Vt, f16* __restrict__ Y)
{
  __shared__ __align__(16) char smem[40960];
  int wg = blockIdx.x;
  int lin = (wg & 7) * 128 + (wg >> 3);
  const int p  = lin & 15;
  const int bh = lin >> 4;
  const int itB = NQT - p;
  const f16* Qb  = Q  + (size_t)bh * Tseq * HDim;
  const f16* Kb  = Kg + (size_t)bh * Tseq * HDim;
  const f16* Vtb = Vt + (size_t)bh * HDim * Tseq;

  const int tid = threadIdx.x, w = tid >> 6, lane = tid & 63;
  const int g = lane >> 4, lm = lane & 15;
  char* pwrow = smem + 32768 + w * 2048 + lm * 128;
  const int b = bh >> 4, h = bh & 15;

  half8 ones;
#pragma unroll
  for (int i = 0; i < 8; ++i) ones[i] = (f16)1.0f;

  int q0 = (NQT - 1 - p) * 64;
  int qg = q0 + w * 16 + lm;
  half8 qf0 = *(const half8*)(Qb + (size_t)(q0 + w * 16 + lm) * HDim + g * 8);
  half8 qf1 = *(const half8*)(Qb + (size_t)(q0 + w * 16 + lm) * HDim + 32 + g * 8);

  floatx4 acc[4], acc5;
  acc5 = (floatx4)0.f;
#pragma unroll
  for (int ng = 0; ng < 4; ++ng) acc[ng] = (floatx4)0.f;

  const int srow = w * 8 + (lane >> 3);
  const int sslot = lane & 7;

  auto stage = [&](int j0s, int buf) {
#pragma unroll
    for (int t = 0; t < 2; ++t) {
      int row = srow + t * 32;
      int cg = sslot ^ (row & 7);
      GLDS16(Kb + (size_t)(j0s + row) * HDim + cg * 8,
             smem + buf * 8192 + (w * 8 + t * 32) * 128);
      GLDS16(Vtb + (size_t)row * Tseq + j0s + cg * 8,
             smem + 16384 + buf * 8192 + (w * 8 + t * 32) * 128);
    }
  };

  auto compute = [&](int j0, int par, bool diag) {
    char* kb   = smem + par * 8192;
    char* vbuf = smem + 16384 + par * 8192;
    floatx4 s[4];
    __builtin_amdgcn_s_setprio(1);
#pragma unroll
    for (int nf = 0; nf < 4; ++nf) {
      half8 kf0 = *(const half8*)(kb + (nf * 16 + lm) * 128 + 16 * ((g)     ^ (lm & 7)));
      half8 kf1 = *(const half8*)(kb + (nf * 16 + lm) * 128 + 16 * ((4 + g) ^ (lm & 7)));
      s[nf] = MFMA16(kf0, qf0, (floatx4)0.f);
      s[nf] = MFMA16(kf1, qf1, s[nf]);
    }
    __builtin_amdgcn_s_setprio(0);

    softmax_tile(s, diag, j0, qg, pwrow, g, lm);
    half8 pa0 = *(const half8*)(pwrow + 16 * ((g)     ^ (lm & 7)));
    half8 pa1 = *(const half8*)(pwrow + 16 * ((4 + g) ^ (lm & 7)));

    __builtin_amdgcn_s_setprio(1);
    acc5 = MFMA16(pa0, ones, acc5);
    acc5 = MFMA16(pa1, ones, acc5);
#pragma unroll
    for (int c = 0; c < 2; ++c)
#pragma unroll
      for (int ng = 0; ng < 4; ++ng) {
        half8 vbf = *(const half8*)(vbuf + (ng * 16 + lm) * 128 + 16 * ((4 * c + g) ^ (lm & 7)));
        acc[ng] = MFMA16(c ? pa1 : pa0, vbf, acc[ng]);
      }
    __builtin_amdgcn_s_setprio(0);
  };

  // prologue
  stage(0, 0);
  asm volatile("s_waitcnt vmcnt(0)" ::: "memory");
  __builtin_amdgcn_s_barrier();

  int git = 0;
  // phase B main: jt affine
  for (int jt = 0; jt < itB - 1; ++jt, ++git) {
    stage((jt + 1) * 64, (git + 1) & 1);
    compute(jt * 64, git & 1, false);
    asm volatile("s_waitcnt vmcnt(0)" ::: "memory");
    __builtin_amdgcn_s_barrier();
  }
  // phase B last (diag): stage phase-A tile 0
  stage(0, (git + 1) & 1);
  compute((itB - 1) * 64, git & 1, true);
  asm volatile("s_waitcnt vmcnt(0)" ::: "memory");
  __builtin_amdgcn_s_barrier();
  ++git;

  store_o(acc, acc5, q0 + 16 * w, g, lm, Y, b, h);
  q0 = p * 64;
  qg = q0 + w * 16 + lm;
  qf0 = *(const half8*)(Qb + (size_t)(q0 + w * 16 + lm) * HDim + g * 8);
  qf1 = *(const half8*)(Qb + (size_t)(q0 + w * 16 + lm) * HDim + 32 + g * 8);
  acc5 = (floatx4)0.f;
#pragma unroll
  for (int ng = 0; ng < 4; ++ng) acc[ng] = (floatx4)0.f;

  // phase A main: jt affine
  for (int jt = 0; jt < p; ++jt, ++git) {
    stage((jt + 1) * 64, (git + 1) & 1);
    compute(jt * 64, git & 1, false);
    asm volatile("s_waitcnt vmcnt(0)" ::: "memory");
    __builtin_amdgcn_s_barrier();
  }
  // phase A last (diag): no stage, no trailing barrier needed
  compute(p * 64, git & 1, true);

  store_o(acc, acc5, q0 + 16 * w, g, lm, Y, b, h);
}

// ---------------- launcher ----------------
extern "C" void kernel_launch(void* const* d_in, const int* in_sizes, int n_in,
                              void* d_out, int out_size, void* d_ws, size_t ws_size,
                              hipStream_t stream)
{
  const float* x      = (const float*)d_in[0];
  const float* W_attn = (const float*)d_in[1];
  const float* W_proj = (const float*)d_in[2];
  float* out = (float*)d_out;

  char* ws = (char*)d_ws;
  f16* xh  = (f16*)(ws);
  f16* wAh = (f16*)(ws + (size_t)(16u << 20));
  f16* wPh = (f16*)(ws + (size_t)(22u << 20));
  f16* Qh  = (f16*)(ws + (size_t)(24u << 20));
  f16* Kh  = (f16*)(ws + (size_t)(40u << 20));
  f16* Vth = (f16*)(ws + (size_t)(56u << 20));  // V^T [B,H,HD,T]
  f16* yh  = xh;

  constexpr int ntot = (Mtok * Cdim + 3 * Cdim * Cdim + Cdim * Cdim) / 4;
  cvt3_kernel<<<(ntot + 255) / 256, 256, 0, stream>>>(x, W_attn, W_proj, xh, wAh, wPh);

  qkvt_kernel<<<dim3(512), 512, 0, stream>>>(xh, wAh, Qh, Kh, Vth);

  attn_kernel<<<dim3(1024), 256, 0, stream>>>(Qh, Kh, Vth, yh);

  proj8p_kernel<<<dim3(256), 512, 0, stream>>>(yh, wPh, out);
}